// Round 2
// baseline (566.848 us; speedup 1.0000x reference)
//
#include <hip/hip_runtime.h>

typedef unsigned short u16;
typedef unsigned int u32;
typedef unsigned long long u64;

typedef __attribute__((ext_vector_type(8))) short short8;   // 8 bf16 = 4 VGPRs
typedef __attribute__((ext_vector_type(4))) float floatx4;  // MFMA accumulator

__device__ __forceinline__ float b2f(u16 h) {
  u32 u = ((u32)h) << 16;
  return __builtin_bit_cast(float, u);
}
__device__ __forceinline__ u16 f2b(float f) {
  u32 u = __builtin_bit_cast(u32, f);
  u32 r = 0x7FFFu + ((u >> 16) & 1u);  // RNE
  return (u16)((u + r) >> 16);
}

// async global->LDS, 16B per lane. LDS dest = wave-uniform base + lane*16.
__device__ __forceinline__ void gl_lds16(const void* g, void* l) {
  __builtin_amdgcn_global_load_lds(
      (__attribute__((address_space(1))) void*)(u64)g,
      (__attribute__((address_space(3))) void*)(u32)(u64)l, 16, 0, 0);
}

enum { EPI_PHI_BIAS = 0, EPI_BIAS = 1, EPI_NONE = 2, EPI_ZSCALE = 3,
       EPI_BIAS_F32 = 4, EPI_ZBIAS_F32 = 5 };

// C[m,n] = sum_k A[m,k] * B[n,k]  (both K-contiguous). 128x128x32 tile, 4 waves.
// Double-buffered LDS; prefetch for tile k+1 issued AFTER the barrier draining
// tile k, overlapping tile k's ds_read+MFMA phase.
// bf16 tiles in LDS: superrow XOR swizzle (R=r>>1, u=((r&1)<<2)|c, phys=R*8+(u^(R&7))).
// A_F32: A NEVER touches LDS. Fragments are loaded fp32 straight from global
// (lane-regular: row = frag row, k = 8q..8q+7 -> 2x dwordx4), prefetched one
// K-step ahead in registers, truncate-packed (v_perm, bit-identical to the old
// staging conversion) at consumption. LDS holds only B -> per-K-step LDS
// traffic 48KB -> 24KB, below the MFMA demand.
// Split-K: blockIdx.z = kslice*(abmask+1)+batch; abz=bz&abmask, kbase=(bz>>kshift)*K.
// DUAL: bz selects operand set 1 (A2/B2/bias2/C2, no phi) vs set 0 (phi).
template<int EPI, bool A_F32, bool TRANS_OUT, bool DUAL>
__global__ __launch_bounds__(256)
void gemm_bt(const void* __restrict__ Aall, const u16* __restrict__ Ball,
             const float* __restrict__ bias, const float* __restrict__ Zall,
             void* __restrict__ Call,
             int M, int N, int K, int ldA, int ldB, int ldC,
             long sAb, long sBb, long sCb, long sZb, int abmask, int kshift,
             const void* __restrict__ Aall2, const u16* __restrict__ Ball2,
             const float* __restrict__ bias2, void* __restrict__ Call2)
{
  constexpr int STRIDE = A_F32 ? 8192 : 16384;    // one stage buffer (B-only vs A+B)
  constexpr int BOFF   = A_F32 ? 0 : 8192;        // B tile offset within buffer
  constexpr int SMEM   = (TRANS_OUT && 34816 > 2 * STRIDE) ? 34816 : 2 * STRIDE;
  __shared__ char smem[SMEM];

  const int tid  = threadIdx.x;
  const int lane = tid & 63;
  const int wave = tid >> 6;
  const int wm = wave >> 1, wn = wave & 1;   // 2x2 waves, 64x64 each
  const int fl = lane & 15;
  const int q  = lane >> 4;
  const int r4 = q * 4;
  const int bm0 = blockIdx.x * 128, bn0 = blockIdx.y * 128;
  const int bz = blockIdx.z;
  const int abz = bz & abmask;
  const int kbase = (bz >> kshift) * K;

  const void* Asel = Aall; const u16* Bsel = Ball;
  const float* biasSel = bias; void* Csel = Call;
  bool phi_on = true;
  if constexpr (DUAL) {
    if (bz) { Asel = Aall2; Bsel = Ball2; biasSel = bias2; Csel = Call2; phi_on = false; }
  }

  const float* Af = (const float*)Asel + (size_t)abz * sAb + kbase;
  const u16*   Ah = (const u16*)Asel + (size_t)abz * sAb + kbase;
  const u16*   Bp = Bsel + (size_t)abz * sBb + kbase;

  // ---- staging addresses (global per-lane; LDS offsets wave-uniform for gl_lds) ----
  const u16* gB[2]; int bL[2];
  #pragma unroll
  for (int n = 0; n < 2; ++n) {
    int j = n * 256 + tid;                 // physical 16B slot in B tile
    int R = j >> 3, u = (j & 7) ^ (R & 7);
    int r = (R << 1) | (u >> 2), c = u & 3;
    gB[n] = Bp + (size_t)(bn0 + r) * ldB + c * 8;
    bL[n] = (n * 256 + wave * 64) * 16;
  }
  const u16* gAh[2]; int aL[2];            // !A_F32: gl_lds path for A
  const float* gAF[4];                     // A_F32: per-fragment global base
  if constexpr (A_F32) {
    #pragma unroll
    for (int i = 0; i < 4; ++i)
      gAF[i] = Af + (size_t)(bm0 + wm * 64 + i * 16 + fl) * ldA + q * 8;
  } else {
    #pragma unroll
    for (int n = 0; n < 2; ++n) {
      int j = n * 256 + tid;
      int R = j >> 3, u = (j & 7) ^ (R & 7);
      int r = (R << 1) | (u >> 2), c = u & 3;
      gAh[n] = Ah + (size_t)(bm0 + r) * ldA + c * 8;
      aL[n] = (n * 256 + wave * 64) * 16;
    }
  }

  // ---- fragment LDS byte offsets (within one stage buffer) ----
  int aoff[4], boff[4];
  #pragma unroll
  for (int i = 0; i < 4; ++i) {
    int rb = wn * 64 + i * 16 + fl;
    int Rb = rb >> 1, ub = ((((rb & 1) << 2) | q) ^ (Rb & 7));
    boff[i] = (Rb * 8 + ub) * 16;
    if constexpr (!A_F32) {
      int ra = wm * 64 + i * 16 + fl;
      int Ra = ra >> 1, ua = ((((ra & 1) << 2) | q) ^ (Ra & 7));
      aoff[i] = (Ra * 8 + ua) * 16;
    }
  }

  floatx4 zero = {0.f, 0.f, 0.f, 0.f};
  floatx4 acc[4][4];
  #pragma unroll
  for (int i = 0; i < 4; ++i)
    #pragma unroll
    for (int j = 0; j < 4; ++j) acc[i][j] = zero;

  auto stageB = [&](int k0, char* base) {
    #pragma unroll
    for (int n = 0; n < 2; ++n) gl_lds16(gB[n] + k0, base + BOFF + bL[n]);
  };

  const int NIT = K >> 5;                 // even for all our shapes
  if constexpr (A_F32) {
    float4 rA[8];                          // next-step raw fp32 fragments
    auto loadAf = [&](int k0) {
      #pragma unroll
      for (int i = 0; i < 4; ++i) {
        rA[2 * i]     = *(const float4*)(gAF[i] + k0);
        rA[2 * i + 1] = *(const float4*)(gAF[i] + k0 + 4);
      }
    };
    short8 aF[4];
    auto convA = [&]() {                   // truncate-pack rA -> aF (bit-identical)
      #pragma unroll
      for (int i = 0; i < 4; ++i) {
        const u32* xb = (const u32*)&rA[2 * i];
        const u32* yb = (const u32*)&rA[2 * i + 1];
        union { u32 w[4]; short8 s; } cv;
        cv.w[0] = __builtin_amdgcn_perm(xb[1], xb[0], 0x07060302u);
        cv.w[1] = __builtin_amdgcn_perm(xb[3], xb[2], 0x07060302u);
        cv.w[2] = __builtin_amdgcn_perm(yb[1], yb[0], 0x07060302u);
        cv.w[3] = __builtin_amdgcn_perm(yb[3], yb[2], 0x07060302u);
        aF[i] = cv.s;
      }
    };
    auto computeB = [&](const char* base) {
      short8 bF[4];
      #pragma unroll
      for (int i = 0; i < 4; ++i) bF[i] = *(const short8*)(base + BOFF + boff[i]);
      #pragma unroll
      for (int mi = 0; mi < 4; ++mi)
        #pragma unroll
        for (int ni = 0; ni < 4; ++ni)
          acc[mi][ni] = __builtin_amdgcn_mfma_f32_16x16x32_bf16(aF[mi], bF[ni], acc[mi][ni], 0, 0, 0);
    };
    loadAf(0);
    stageB(0, smem);
    for (int it = 0; it < NIT; it += 2) {
      __syncthreads();                     // buf0 B-DMA drained
      if (it + 1 < NIT) stageB((it + 1) * 32, smem + STRIDE);
      convA();                             // step it (waits rA loads)
      if (it + 1 < NIT) loadAf((it + 1) * 32);   // lands under compute+barrier
      computeB(smem);
      __syncthreads();                     // buf1 B-DMA drained
      if (it + 2 < NIT) stageB((it + 2) * 32, smem);
      convA();                             // step it+1
      if (it + 2 < NIT) loadAf((it + 2) * 32);
      computeB(smem + STRIDE);
    }
  } else {
    auto compute = [&](const char* base) {
      short8 aF[4], bF[4];
      #pragma unroll
      for (int i = 0; i < 4; ++i) aF[i] = *(const short8*)(base + aoff[i]);
      #pragma unroll
      for (int i = 0; i < 4; ++i) bF[i] = *(const short8*)(base + BOFF + boff[i]);
      #pragma unroll
      for (int mi = 0; mi < 4; ++mi)
        #pragma unroll
        for (int ni = 0; ni < 4; ++ni)
          acc[mi][ni] = __builtin_amdgcn_mfma_f32_16x16x32_bf16(aF[mi], bF[ni], acc[mi][ni], 0, 0, 0);
    };
    auto stageA = [&](int k0, char* base) {
      #pragma unroll
      for (int n = 0; n < 2; ++n) gl_lds16(gAh[n] + k0, base + aL[n]);
    };
    stageA(0, smem); stageB(0, smem);
    for (int it = 0; it < NIT; it += 2) {
      __syncthreads();                    // drains buf0 loads; prev buf1 reads done
      if (it + 1 < NIT) { stageA((it + 1) * 32, smem + STRIDE); stageB((it + 1) * 32, smem + STRIDE); }
      compute(smem);
      __syncthreads();                    // drains buf1 loads; buf0 reads done
      if (it + 2 < NIT) { stageA((it + 2) * 32, smem); stageB((it + 2) * 32, smem); }
      compute(smem + STRIDE);
    }
  }

  if constexpr (!TRANS_OUT) {
    #pragma unroll
    for (int mi = 0; mi < 4; ++mi) {
      #pragma unroll
      for (int ni = 0; ni < 4; ++ni) {
        int col = bn0 + wn * 64 + ni * 16 + fl;
        #pragma unroll
        for (int r = 0; r < 4; ++r) {
          int row = bm0 + wm * 64 + mi * 16 + r4 + r;
          float vv = acc[mi][ni][r];
          if constexpr (EPI == EPI_PHI_BIAS) {
            vv += biasSel[col];
            if (phi_on) vv = __expf(-0.5f * vv * vv);
          }
          if constexpr (EPI == EPI_BIAS || EPI == EPI_BIAS_F32) vv += biasSel[col];
          if constexpr (EPI == EPI_ZSCALE) vv *= Zall[(size_t)abz * sZb + row];
          if constexpr (EPI == EPI_ZBIAS_F32)
            vv = vv * Zall[(size_t)abz * sZb + row] + biasSel[col];
          if constexpr (EPI == EPI_BIAS_F32 || EPI == EPI_ZBIAS_F32)
            ((float*)Csel)[(size_t)bz * sCb + (size_t)row * ldC + col] = vv;
          else
            ((u16*)Csel)[(size_t)bz * sCb + (size_t)row * ldC + col] = f2b(vv);
        }
      }
    }
  } else {
    // transpose tile through LDS, then coalesced 16B stores into [4][N][4096]
    __syncthreads();
    u16* sT = (u16*)smem;  // [128][136] = 34816 B
    #pragma unroll
    for (int mi = 0; mi < 4; ++mi) {
      #pragma unroll
      for (int ni = 0; ni < 4; ++ni) {
        int colL = wn * 64 + ni * 16 + fl;
        int row0 = wm * 64 + mi * 16 + r4;
        float bcol = biasSel[bn0 + colL];
        ushort4 h;
        #pragma unroll
        for (int r = 0; r < 4; ++r) {
          float vv = acc[mi][ni][r] + bcol;
          if (phi_on) vv = __expf(-0.5f * vv * vv);
          ((u16*)&h)[r] = f2b(vv);
        }
        *(ushort4*)(sT + colL * 136 + row0) = h;
      }
    }
    __syncthreads();
    #pragma unroll
    for (int i = 0; i < 8; ++i) {
      int c = tid + i * 256;                // 2048 x 16B chunks
      int dloc = c >> 4, t8 = (c & 15) * 8;
      int4 vv = *(const int4*)(sT + dloc * 136 + t8);
      int gd = bn0 + dloc;
      int gt = bm0 + t8;
      int batch = gt >> 12, tt = gt & 4095;
      *(int4*)((u16*)Csel + ((size_t)batch * N + gd) * 4096 + tt) = vv;
    }
  }
}

__global__ __launch_bounds__(256)
void wconv(const float* __restrict__ w0, const float* __restrict__ w1,
           const float* __restrict__ w2, const float* __restrict__ w3,
           u16* __restrict__ dst) {
  unsigned e = blockIdx.x * 256 + threadIdx.x;
  int mat = e >> 18;
  size_t off = (size_t)(e & 262143) * 4;
  const float* src = mat == 0 ? w0 : mat == 1 ? w1 : mat == 2 ? w2 : w3;
  float4 v = *(const float4*)(src + off);
  ushort4 h;
  h.x = f2b(v.x); h.y = f2b(v.y); h.z = f2b(v.z); h.w = f2b(v.w);
  *(ushort4*)(dst + (size_t)mat * 1048576 + off) = h;
}

// out[i] = round(sum over 4 K-slices of bf16 partials), 4M elems, slice stride 4M
__global__ __launch_bounds__(256)
void reduce4(const u16* __restrict__ P, u16* __restrict__ out) {
  size_t i = ((size_t)blockIdx.x * 256 + threadIdx.x) * 8;
  int4 a = *(const int4*)(P + i);
  int4 b = *(const int4*)(P + i + 4194304);
  int4 c = *(const int4*)(P + i + 8388608);
  int4 d = *(const int4*)(P + i + 12582912);
  const u16* ha = (const u16*)&a; const u16* hb = (const u16*)&b;
  const u16* hc = (const u16*)&c; const u16* hd = (const u16*)&d;
  ushort4 o0, o1;
  #pragma unroll
  for (int j = 0; j < 8; ++j) {
    float s = b2f(ha[j]) + b2f(hb[j]) + b2f(hc[j]) + b2f(hd[j]);
    ((u16*)(j < 4 ? &o0 : &o1))[j & 3] = f2b(s);
  }
  *(ushort4*)(out + i) = o0;
  *(ushort4*)(out + i + 4) = o1;
}

// Ksum[b*1024+d] = sum_t KT[b][d][t]; one wave per (b,d) row
__global__ __launch_bounds__(256)
void ksum_rows(const u16* __restrict__ KT, float* __restrict__ Ksum) {
  int lane = threadIdx.x & 63;
  int row = blockIdx.x * 4 + (threadIdx.x >> 6);
  const u16* p = KT + (size_t)row * 4096;
  float s = 0.f;
  #pragma unroll
  for (int i = 0; i < 8; ++i) {
    int4 d = *(const int4*)(p + i * 512 + lane * 8);
    const u16* h = (const u16*)&d;
    #pragma unroll
    for (int j = 0; j < 8; ++j) s += b2f(h[j]);
  }
  #pragma unroll
  for (int off = 32; off; off >>= 1) s += __shfl_xor(s, off, 64);
  if (lane == 0) Ksum[row] = s;
}

// Z[t] = 1/(Q[t,:]·Ksum[batch,:] + 1e-6); one wave per token
__global__ __launch_bounds__(256)
void zden(const u16* __restrict__ Qb, const float* __restrict__ Ksum,
          float* __restrict__ Z) {
  int lane = threadIdx.x & 63;
  int t = blockIdx.x * 4 + (threadIdx.x >> 6);
  const u16* qp = Qb + (size_t)t * 1024;
  const float* ks = Ksum + (size_t)(t >> 12) * 1024;
  float s = 0.f;
  #pragma unroll
  for (int i = 0; i < 2; ++i) {
    int idx = i * 512 + lane * 8;
    int4 d = *(const int4*)(qp + idx);
    const u16* h = (const u16*)&d;
    float4 k0 = *(const float4*)(ks + idx);
    float4 k1 = *(const float4*)(ks + idx + 4);
    s += b2f(h[0]) * k0.x + b2f(h[1]) * k0.y + b2f(h[2]) * k0.z + b2f(h[3]) * k0.w
       + b2f(h[4]) * k1.x + b2f(h[5]) * k1.y + b2f(h[6]) * k1.z + b2f(h[7]) * k1.w;
  }
  #pragma unroll
  for (int off = 32; off; off >>= 1) s += __shfl_xor(s, off, 64);
  if (lane == 0) Z[t] = 1.0f / (s + 1e-6f);
}

extern "C" void kernel_launch(void* const* d_in, const int* in_sizes, int n_in,
                              void* d_out, int out_size, void* d_ws, size_t ws_size,
                              hipStream_t stream) {
  const float* q  = (const float*)d_in[0];
  const float* k  = (const float*)d_in[1];
  const float* v  = (const float*)d_in[2];
  const float* Wq = (const float*)d_in[3];
  const float* bq = (const float*)d_in[4];
  const float* Wk = (const float*)d_in[5];
  const float* bk = (const float*)d_in[6];
  const float* Wv = (const float*)d_in[7];
  const float* bv = (const float*)d_in[8];
  const float* Wo = (const float*)d_in[9];
  const float* bo = (const float*)d_in[10];
  float* out = (float*)d_out;

  // workspace layout (~112.1 MiB) with aliasing:
  u16* Wqb = (u16*)d_ws;                 // 4x 1024x1024 bf16 = 8 MiB
  u16* Wkb = Wqb + 1048576;
  u16* Wvb = Wkb + 1048576;
  u16* Wob = Wvb + 1048576;
  u16* Qb  = Wob + 1048576;              // [16384][1024] bf16, 32 MiB
  u16* KT  = Qb  + 16777216;             // [4][1024][4096] bf16, 32 MiB
  u16* VT  = KT  + 16777216;             // [4][1024][4096] bf16, 32 MiB
  u16* KVr = VT  + 16777216;             // [4][1024(d)][1024(l)] bf16, 8 MiB
  float* Ksum = (float*)(KVr + 4194304); // [4][1024] f32
  float* Z    = Ksum + 4096;             // [16384] f32
  u16* Pkv = Qb;   // S2 split-K partials, before Q-proj overwrites
  u16* Pg  = VT;   // G split-K partials, after VT dead
  u16* Gp  = KT;   // G' [4][1024(n)][1024(d)], after KT dead

  wconv<<<4096, 256, 0, stream>>>(Wq, Wk, Wv, Wo, Wqb);

  // K,V projections in ONE dispatch (grid z: 0=K with phi, 1=V bias-only).
  dim3 gkv(128, 8, 2);
  gemm_bt<EPI_PHI_BIAS, true, true, true><<<gkv, 256, 0, stream>>>(
      k, Wkb, bk, nullptr, KT, 16384, 1024, 1024, 1024, 1024, 0,
      0, 0, 0, 0, 0, 30, v, Wvb, bv, VT);

  ksum_rows<<<1024, 256, 0, stream>>>(KT, Ksum);

  // S2: KVr[d,l] = sum_t KT[d,t]*VT[l,t], split-K x4 (z = kslice*4+batch)
  dim3 g2(8, 8, 16);
  gemm_bt<EPI_NONE, false, false, false><<<g2, 256, 0, stream>>>(
      KT, VT, nullptr, nullptr, Pkv, 1024, 1024, 1024, 4096, 4096, 1024,
      4194304L, 4194304L, 1048576L, 0, 3, 2, nullptr, nullptr, nullptr, nullptr);
  reduce4<<<2048, 256, 0, stream>>>(Pkv, KVr);

  // Q projection (overwrites partials region — stream-ordered after reduce)
  dim3 g1(128, 8, 1);
  gemm_bt<EPI_PHI_BIAS, true, false, false><<<g1, 256, 0, stream>>>(
      q, Wqb, bq, nullptr, Qb, 16384, 1024, 1024, 1024, 1024, 1024,
      0, 0, 0, 0, 0, 30, nullptr, nullptr, nullptr, nullptr);

  zden<<<4096, 256, 0, stream>>>(Qb, Ksum, Z);

  // G'[n,d] = sum_l Wob[n,l]*KVr[d,l], split-K x4 (K=256/slice); Wo folded in.
  dim3 gg(8, 8, 16);
  gemm_bt<EPI_NONE, false, false, false><<<gg, 256, 0, stream>>>(
      Wob, KVr, nullptr, nullptr, Pg, 1024, 1024, 256, 1024, 1024, 1024,
      0L, 1048576L, 1048576L, 0, 3, 2, nullptr, nullptr, nullptr, nullptr);
  reduce4<<<2048, 256, 0, stream>>>(Pg, Gp);

  // final: out[t,n] = Z[t]*(sum_d Qb[t,d]*G'[n,d]) + bo[n], fp32 out
  dim3 gf(32, 8, 4);
  gemm_bt<EPI_ZBIAS_F32, false, false, false><<<gf, 256, 0, stream>>>(
      Qb, Gp, bo, Z, out, 4096, 1024, 1024, 1024, 1024, 1024,
      4194304L, 1048576L, 4194304L, 4096L, 3, 30, nullptr, nullptr, nullptr, nullptr);
}

// Round 3
// 409.867 us; speedup vs baseline: 1.3830x; 1.3830x over previous
//
#include <hip/hip_runtime.h>

typedef unsigned short u16;
typedef unsigned int u32;
typedef unsigned long long u64;

typedef __attribute__((ext_vector_type(8))) short short8;   // 8 bf16 = 4 VGPRs
typedef __attribute__((ext_vector_type(4))) float floatx4;  // MFMA accumulator

__device__ __forceinline__ float b2f(u16 h) {
  u32 u = ((u32)h) << 16;
  return __builtin_bit_cast(float, u);
}
__device__ __forceinline__ u16 f2b(float f) {
  u32 u = __builtin_bit_cast(u32, f);
  u32 r = 0x7FFFu + ((u >> 16) & 1u);  // RNE
  return (u16)((u + r) >> 16);
}

// async global->LDS, 16B per lane. LDS dest = wave-uniform base + lane*16.
__device__ __forceinline__ void gl_lds16(const void* g, void* l) {
  __builtin_amdgcn_global_load_lds(
      (__attribute__((address_space(1))) void*)(u64)g,
      (__attribute__((address_space(3))) void*)(u32)(u64)l, 16, 0, 0);
}

enum { EPI_PHI_BIAS = 0, EPI_BIAS = 1, EPI_NONE = 2, EPI_ZSCALE = 3,
       EPI_BIAS_F32 = 4, EPI_ZBIAS_F32 = 5 };

// C[m,n] = sum_k A[m,k] * B[n,k]  (both K-contiguous). 128x128x32 tile, 4 waves.
// 3-stage LDS ring with COUNTED vmcnt (T3+T4): stage for step n+2 issued at top
// of step n (~2 K-steps of latency cover); barrier waits vmcnt(6)/vmcnt(4) (the
// next stage stays in flight), never vmcnt(0) in the loop. Raw s_barrier fused
// into one asm with the waitcnt ("memory") so nothing reorders across it.
// bf16 tiles in LDS: superrow XOR swizzle (R=r>>1, u=((r&1)<<2)|c, phys=R*8+(u^(R&7))).
// A_F32: A never touches LDS. Wave decomposition is 4x1 (each wave owns 32
// DISTINCT rows x 128 cols, acc[2][8]) so A is fetched exactly once (no wm-pair
// duplication). Per-fragment fp32 loads prefetched 2 steps ahead into two
// STATIC register sets (unroll x2), truncate-packed (v_perm, bit-identical).
// Split-K: blockIdx.z = kslice*(abmask+1)+batch; abz=bz&abmask, kbase=(bz>>kshift)*K.
// DUAL: bz selects operand set 1 (A2/B2/bias2/C2, no phi) vs set 0 (phi).
template<int EPI, bool A_F32, bool TRANS_OUT, bool DUAL>
__global__ __launch_bounds__(256)
void gemm_bt(const void* __restrict__ Aall, const u16* __restrict__ Ball,
             const float* __restrict__ bias, const float* __restrict__ Zall,
             void* __restrict__ Call,
             int M, int N, int K, int ldA, int ldB, int ldC,
             long sAb, long sBb, long sCb, long sZb, int abmask, int kshift,
             const void* __restrict__ Aall2, const u16* __restrict__ Ball2,
             const float* __restrict__ bias2, void* __restrict__ Call2)
{
  constexpr int BSTRIDE = A_F32 ? 8192 : 16384;   // one ring buffer (B-only vs A+B)
  constexpr int BOFF    = A_F32 ? 0 : 8192;       // B tile offset within buffer
  constexpr int SMEM3   = 3 * BSTRIDE;
  constexpr int SMEM    = (TRANS_OUT && 34816 > SMEM3) ? 34816 : SMEM3;
  __shared__ char smem[SMEM];

  constexpr int MI = A_F32 ? 2 : 4;               // M fragments per wave
  constexpr int NI = A_F32 ? 8 : 4;               // N fragments per wave

  const int tid  = threadIdx.x;
  const int lane = tid & 63;
  const int wave = tid >> 6;
  const int wm = wave >> 1, wn = wave & 1;   // 2x2 decomposition (!A_F32)
  const int fl = lane & 15;
  const int q  = lane >> 4;
  const int r4 = q * 4;
  const int rowB = A_F32 ? wave * 32 : wm * 64;   // wave's row base in tile
  const int colB = A_F32 ? 0 : wn * 64;           // wave's col base in tile
  const int bm0 = blockIdx.x * 128, bn0 = blockIdx.y * 128;
  const int bz = blockIdx.z;
  const int abz = bz & abmask;
  const int kbase = (bz >> kshift) * K;

  const void* Asel = Aall; const u16* Bsel = Ball;
  const float* biasSel = bias; void* Csel = Call;
  bool phi_on = true;
  if constexpr (DUAL) {
    if (bz) { Asel = Aall2; Bsel = Ball2; biasSel = bias2; Csel = Call2; phi_on = false; }
  }

  const float* Af = (const float*)Asel + (size_t)abz * sAb + kbase;
  const u16*   Ah = (const u16*)Asel + (size_t)abz * sAb + kbase;
  const u16*   Bp = Bsel + (size_t)abz * sBb + kbase;

  // ---- staging addresses (global per-lane; LDS offsets wave-uniform for gl_lds) ----
  const u16* gB[2]; int bL[2];
  #pragma unroll
  for (int n = 0; n < 2; ++n) {
    int j = n * 256 + tid;                 // physical 16B slot in B tile
    int R = j >> 3, u = (j & 7) ^ (R & 7);
    int r = (R << 1) | (u >> 2), c = u & 3;
    gB[n] = Bp + (size_t)(bn0 + r) * ldB + c * 8;
    bL[n] = (n * 256 + wave * 64) * 16;
  }
  const u16* gAh[2]; int aL[2];            // !A_F32: gl_lds path for A
  const float* gAF[2];                     // A_F32: per-fragment global base
  if constexpr (A_F32) {
    #pragma unroll
    for (int i = 0; i < 2; ++i)
      gAF[i] = Af + (size_t)(bm0 + rowB + i * 16 + fl) * ldA + q * 8;
  } else {
    #pragma unroll
    for (int n = 0; n < 2; ++n) {
      int j = n * 256 + tid;
      int R = j >> 3, u = (j & 7) ^ (R & 7);
      int r = (R << 1) | (u >> 2), c = u & 3;
      gAh[n] = Ah + (size_t)(bm0 + r) * ldA + c * 8;
      aL[n] = (n * 256 + wave * 64) * 16;
    }
  }

  // ---- fragment LDS byte offsets (within one ring buffer) ----
  int aoff[4], boff[NI];
  #pragma unroll
  for (int i = 0; i < NI; ++i) {
    int rb = colB + i * 16 + fl;
    int Rb = rb >> 1, ub = ((((rb & 1) << 2) | q) ^ (Rb & 7));
    boff[i] = (Rb * 8 + ub) * 16;
  }
  if constexpr (!A_F32) {
    #pragma unroll
    for (int i = 0; i < 4; ++i) {
      int ra = rowB + i * 16 + fl;
      int Ra = ra >> 1, ua = ((((ra & 1) << 2) | q) ^ (Ra & 7));
      aoff[i] = (Ra * 8 + ua) * 16;
    }
  }

  floatx4 zero = {0.f, 0.f, 0.f, 0.f};
  floatx4 acc[MI][NI];
  #pragma unroll
  for (int i = 0; i < MI; ++i)
    #pragma unroll
    for (int j = 0; j < NI; ++j) acc[i][j] = zero;

  auto stageB = [&](int k0, char* base) {
    #pragma unroll
    for (int n = 0; n < 2; ++n) gl_lds16(gB[n] + k0, base + BOFF + bL[n]);
  };

  const int NIT = K >> 5;                 // even for all our shapes (8 or 32)
  if constexpr (A_F32) {
    float4 rA0[4], rA1[4];                // two STATIC prefetch sets (rule #20)
    short8 aF[2];
    auto loadA = [&](int k0, float4* r) {
      #pragma unroll
      for (int i = 0; i < 2; ++i) {
        r[2 * i]     = *(const float4*)(gAF[i] + k0);
        r[2 * i + 1] = *(const float4*)(gAF[i] + k0 + 4);
      }
    };
    auto convA = [&](const float4* r) {   // truncate-pack (bit-identical to R1)
      #pragma unroll
      for (int i = 0; i < 2; ++i) {
        const u32* xb = (const u32*)&r[2 * i];
        const u32* yb = (const u32*)&r[2 * i + 1];
        union { u32 w[4]; short8 s; } cv;
        cv.w[0] = __builtin_amdgcn_perm(xb[1], xb[0], 0x07060302u);
        cv.w[1] = __builtin_amdgcn_perm(xb[3], xb[2], 0x07060302u);
        cv.w[2] = __builtin_amdgcn_perm(yb[1], yb[0], 0x07060302u);
        cv.w[3] = __builtin_amdgcn_perm(yb[3], yb[2], 0x07060302u);
        aF[i] = cv.s;
      }
    };
    auto kstep = [&](const char* bufc) {
      #pragma unroll
      for (int h = 0; h < 2; ++h) {
        short8 bF[4];
        #pragma unroll
        for (int i = 0; i < 4; ++i) bF[i] = *(const short8*)(bufc + boff[h * 4 + i]);
        __builtin_amdgcn_s_setprio(1);
        #pragma unroll
        for (int mi = 0; mi < 2; ++mi)
          #pragma unroll
          for (int i = 0; i < 4; ++i)
            acc[mi][h * 4 + i] = __builtin_amdgcn_mfma_f32_16x16x32_bf16(
                aF[mi], bF[i], acc[mi][h * 4 + i], 0, 0, 0);
        __builtin_amdgcn_s_setprio(0);
      }
    };
    stageB(0, smem);            loadA(0, rA0);
    stageB(32, smem + BSTRIDE); loadA(32, rA1);
    convA(rA0);                                    // step 0 fragments ready
    asm volatile("s_waitcnt vmcnt(6)\ns_barrier" ::: "memory");
    int c0 = 0, c2 = 2 * BSTRIDE;
    for (int n = 0; n < NIT; n += 2) {
      {                                            // even step n (aF = A(n))
        bool pf = n + 2 < NIT;
        if (pf) { stageB((n + 2) * 32, smem + c2); loadA((n + 2) * 32, rA0); }
        kstep(smem + c0);
        convA(rA1);                                // A(n+1); auto-waits L(n+1)
        if (pf) asm volatile("s_waitcnt vmcnt(6) lgkmcnt(0)\ns_barrier" ::: "memory");
        else    asm volatile("s_waitcnt vmcnt(0) lgkmcnt(0)\ns_barrier" ::: "memory");
        c0 = c0 == 2 * BSTRIDE ? 0 : c0 + BSTRIDE;
        c2 = c2 == 2 * BSTRIDE ? 0 : c2 + BSTRIDE;
      }
      {                                            // odd step n+1 (aF = A(n+1))
        bool pf = n + 3 < NIT;
        if (pf) { stageB((n + 3) * 32, smem + c2); loadA((n + 3) * 32, rA1); }
        kstep(smem + c0);
        if (n + 2 < NIT) {
          convA(rA0);                              // A(n+2)
          if (pf) asm volatile("s_waitcnt vmcnt(6) lgkmcnt(0)\ns_barrier" ::: "memory");
          else    asm volatile("s_waitcnt vmcnt(0) lgkmcnt(0)\ns_barrier" ::: "memory");
        }
        c0 = c0 == 2 * BSTRIDE ? 0 : c0 + BSTRIDE;
        c2 = c2 == 2 * BSTRIDE ? 0 : c2 + BSTRIDE;
      }
    }
  } else {
    auto stageA = [&](int k0, char* base) {
      #pragma unroll
      for (int n = 0; n < 2; ++n) gl_lds16(gAh[n] + k0, base + aL[n]);
    };
    auto kstep = [&](const char* bufc) {
      short8 aF[4], bF[4];
      #pragma unroll
      for (int i = 0; i < 4; ++i) aF[i] = *(const short8*)(bufc + aoff[i]);
      #pragma unroll
      for (int i = 0; i < 4; ++i) bF[i] = *(const short8*)(bufc + BOFF + boff[i]);
      __builtin_amdgcn_s_setprio(1);
      #pragma unroll
      for (int mi = 0; mi < 4; ++mi)
        #pragma unroll
        for (int ni = 0; ni < 4; ++ni)
          acc[mi][ni] = __builtin_amdgcn_mfma_f32_16x16x32_bf16(
              aF[mi], bF[ni], acc[mi][ni], 0, 0, 0);
      __builtin_amdgcn_s_setprio(0);
    };
    stageA(0, smem);            stageB(0, smem);
    stageA(32, smem + BSTRIDE); stageB(32, smem + BSTRIDE);
    asm volatile("s_waitcnt vmcnt(4)\ns_barrier" ::: "memory");
    int c0 = 0, c2 = 2 * BSTRIDE;
    for (int n = 0; n < NIT; ++n) {
      bool pf = n + 2 < NIT;
      if (pf) { stageA((n + 2) * 32, smem + c2); stageB((n + 2) * 32, smem + c2); }
      kstep(smem + c0);
      if (n + 1 < NIT) {
        if (pf) asm volatile("s_waitcnt vmcnt(4) lgkmcnt(0)\ns_barrier" ::: "memory");
        else    asm volatile("s_waitcnt vmcnt(0) lgkmcnt(0)\ns_barrier" ::: "memory");
      }
      c0 = c0 == 2 * BSTRIDE ? 0 : c0 + BSTRIDE;
      c2 = c2 == 2 * BSTRIDE ? 0 : c2 + BSTRIDE;
    }
  }

  if constexpr (!TRANS_OUT) {
    #pragma unroll
    for (int mi = 0; mi < MI; ++mi) {
      #pragma unroll
      for (int ni = 0; ni < NI; ++ni) {
        int col = bn0 + colB + ni * 16 + fl;
        #pragma unroll
        for (int r = 0; r < 4; ++r) {
          int row = bm0 + rowB + mi * 16 + r4 + r;
          float vv = acc[mi][ni][r];
          if constexpr (EPI == EPI_PHI_BIAS) {
            vv += biasSel[col];
            if (phi_on) vv = __expf(-0.5f * vv * vv);
          }
          if constexpr (EPI == EPI_BIAS || EPI == EPI_BIAS_F32) vv += biasSel[col];
          if constexpr (EPI == EPI_ZSCALE) vv *= Zall[(size_t)abz * sZb + row];
          if constexpr (EPI == EPI_ZBIAS_F32)
            vv = vv * Zall[(size_t)abz * sZb + row] + biasSel[col];
          if constexpr (EPI == EPI_BIAS_F32 || EPI == EPI_ZBIAS_F32)
            ((float*)Csel)[(size_t)bz * sCb + (size_t)row * ldC + col] = vv;
          else
            ((u16*)Csel)[(size_t)bz * sCb + (size_t)row * ldC + col] = f2b(vv);
        }
      }
    }
  } else {
    // transpose tile through LDS, then coalesced 16B stores into [4][N][4096]
    __syncthreads();
    u16* sT = (u16*)smem;  // [128][136] = 34816 B
    #pragma unroll
    for (int mi = 0; mi < MI; ++mi) {
      #pragma unroll
      for (int ni = 0; ni < NI; ++ni) {
        int colL = colB + ni * 16 + fl;
        int row0 = rowB + mi * 16 + r4;
        float bcol = biasSel[bn0 + colL];
        ushort4 h;
        #pragma unroll
        for (int r = 0; r < 4; ++r) {
          float vv = acc[mi][ni][r] + bcol;
          if (phi_on) vv = __expf(-0.5f * vv * vv);
          ((u16*)&h)[r] = f2b(vv);
        }
        *(ushort4*)(sT + colL * 136 + row0) = h;
      }
    }
    __syncthreads();
    #pragma unroll
    for (int i = 0; i < 8; ++i) {
      int c = tid + i * 256;                // 2048 x 16B chunks
      int dloc = c >> 4, t8 = (c & 15) * 8;
      int4 vv = *(const int4*)(sT + dloc * 136 + t8);
      int gd = bn0 + dloc;
      int gt = bm0 + t8;
      int batch = gt >> 12, tt = gt & 4095;
      *(int4*)((u16*)Csel + ((size_t)batch * N + gd) * 4096 + tt) = vv;
    }
  }
}

__global__ __launch_bounds__(256)
void wconv(const float* __restrict__ w0, const float* __restrict__ w1,
           const float* __restrict__ w2, const float* __restrict__ w3,
           u16* __restrict__ dst) {
  unsigned e = blockIdx.x * 256 + threadIdx.x;
  int mat = e >> 18;
  size_t off = (size_t)(e & 262143) * 4;
  const float* src = mat == 0 ? w0 : mat == 1 ? w1 : mat == 2 ? w2 : w3;
  float4 v = *(const float4*)(src + off);
  ushort4 h;
  h.x = f2b(v.x); h.y = f2b(v.y); h.z = f2b(v.z); h.w = f2b(v.w);
  *(ushort4*)(dst + (size_t)mat * 1048576 + off) = h;
}

// out[i] = round(sum over 4 K-slices of bf16 partials), 4M elems, slice stride 4M
__global__ __launch_bounds__(256)
void reduce4(const u16* __restrict__ P, u16* __restrict__ out) {
  size_t i = ((size_t)blockIdx.x * 256 + threadIdx.x) * 8;
  int4 a = *(const int4*)(P + i);
  int4 b = *(const int4*)(P + i + 4194304);
  int4 c = *(const int4*)(P + i + 8388608);
  int4 d = *(const int4*)(P + i + 12582912);
  const u16* ha = (const u16*)&a; const u16* hb = (const u16*)&b;
  const u16* hc = (const u16*)&c; const u16* hd = (const u16*)&d;
  ushort4 o0, o1;
  #pragma unroll
  for (int j = 0; j < 8; ++j) {
    float s = b2f(ha[j]) + b2f(hb[j]) + b2f(hc[j]) + b2f(hd[j]);
    ((u16*)(j < 4 ? &o0 : &o1))[j & 3] = f2b(s);
  }
  *(ushort4*)(out + i) = o0;
  *(ushort4*)(out + i + 4) = o1;
}

// Ksum[b*1024+d] = sum_t KT[b][d][t]; one wave per (b,d) row
__global__ __launch_bounds__(256)
void ksum_rows(const u16* __restrict__ KT, float* __restrict__ Ksum) {
  int lane = threadIdx.x & 63;
  int row = blockIdx.x * 4 + (threadIdx.x >> 6);
  const u16* p = KT + (size_t)row * 4096;
  float s = 0.f;
  #pragma unroll
  for (int i = 0; i < 8; ++i) {
    int4 d = *(const int4*)(p + i * 512 + lane * 8);
    const u16* h = (const u16*)&d;
    #pragma unroll
    for (int j = 0; j < 8; ++j) s += b2f(h[j]);
  }
  #pragma unroll
  for (int off = 32; off; off >>= 1) s += __shfl_xor(s, off, 64);
  if (lane == 0) Ksum[row] = s;
}

// Z[t] = 1/(Q[t,:]·Ksum[batch,:] + 1e-6); one wave per token
__global__ __launch_bounds__(256)
void zden(const u16* __restrict__ Qb, const float* __restrict__ Ksum,
          float* __restrict__ Z) {
  int lane = threadIdx.x & 63;
  int t = blockIdx.x * 4 + (threadIdx.x >> 6);
  const u16* qp = Qb + (size_t)t * 1024;
  const float* ks = Ksum + (size_t)(t >> 12) * 1024;
  float s = 0.f;
  #pragma unroll
  for (int i = 0; i < 2; ++i) {
    int idx = i * 512 + lane * 8;
    int4 d = *(const int4*)(qp + idx);
    const u16* h = (const u16*)&d;
    float4 k0 = *(const float4*)(ks + idx);
    float4 k1 = *(const float4*)(ks + idx + 4);
    s += b2f(h[0]) * k0.x + b2f(h[1]) * k0.y + b2f(h[2]) * k0.z + b2f(h[3]) * k0.w
       + b2f(h[4]) * k1.x + b2f(h[5]) * k1.y + b2f(h[6]) * k1.z + b2f(h[7]) * k1.w;
  }
  #pragma unroll
  for (int off = 32; off; off >>= 1) s += __shfl_xor(s, off, 64);
  if (lane == 0) Z[t] = 1.0f / (s + 1e-6f);
}

extern "C" void kernel_launch(void* const* d_in, const int* in_sizes, int n_in,
                              void* d_out, int out_size, void* d_ws, size_t ws_size,
                              hipStream_t stream) {
  const float* q  = (const float*)d_in[0];
  const float* k  = (const float*)d_in[1];
  const float* v  = (const float*)d_in[2];
  const float* Wq = (const float*)d_in[3];
  const float* bq = (const float*)d_in[4];
  const float* Wk = (const float*)d_in[5];
  const float* bk = (const float*)d_in[6];
  const float* Wv = (const float*)d_in[7];
  const float* bv = (const float*)d_in[8];
  const float* Wo = (const float*)d_in[9];
  const float* bo = (const float*)d_in[10];
  float* out = (float*)d_out;

  // workspace layout (~112.1 MiB) with aliasing:
  u16* Wqb = (u16*)d_ws;                 // 4x 1024x1024 bf16 = 8 MiB
  u16* Wkb = Wqb + 1048576;
  u16* Wvb = Wkb + 1048576;
  u16* Wob = Wvb + 1048576;
  u16* Qb  = Wob + 1048576;              // [16384][1024] bf16, 32 MiB
  u16* KT  = Qb  + 16777216;             // [4][1024][4096] bf16, 32 MiB
  u16* VT  = KT  + 16777216;             // [4][1024][4096] bf16, 32 MiB
  u16* KVr = VT  + 16777216;             // [4][1024(d)][1024(l)] bf16, 8 MiB
  float* Ksum = (float*)(KVr + 4194304); // [4][1024] f32
  float* Z    = Ksum + 4096;             // [16384] f32
  u16* Pkv = Qb;   // S2 split-K partials, before Q-proj overwrites
  u16* Pg  = VT;   // G split-K partials, after VT dead
  u16* Gp  = KT;   // G' [4][1024(n)][1024(d)], after KT dead

  wconv<<<4096, 256, 0, stream>>>(Wq, Wk, Wv, Wo, Wqb);

  // K,V projections in ONE dispatch (grid z: 0=K with phi, 1=V bias-only).
  dim3 gkv(128, 8, 2);
  gemm_bt<EPI_PHI_BIAS, true, true, true><<<gkv, 256, 0, stream>>>(
      k, Wkb, bk, nullptr, KT, 16384, 1024, 1024, 1024, 1024, 0,
      0, 0, 0, 0, 0, 30, v, Wvb, bv, VT);

  ksum_rows<<<1024, 256, 0, stream>>>(KT, Ksum);

  // S2: KVr[d,l] = sum_t KT[d,t]*VT[l,t], split-K x4 (z = kslice*4+batch)
  dim3 g2(8, 8, 16);
  gemm_bt<EPI_NONE, false, false, false><<<g2, 256, 0, stream>>>(
      KT, VT, nullptr, nullptr, Pkv, 1024, 1024, 1024, 4096, 4096, 1024,
      4194304L, 4194304L, 1048576L, 0, 3, 2, nullptr, nullptr, nullptr, nullptr);
  reduce4<<<2048, 256, 0, stream>>>(Pkv, KVr);

  // Q projection (overwrites partials region — stream-ordered after reduce)
  dim3 g1(128, 8, 1);
  gemm_bt<EPI_PHI_BIAS, true, false, false><<<g1, 256, 0, stream>>>(
      q, Wqb, bq, nullptr, Qb, 16384, 1024, 1024, 1024, 1024, 1024,
      0, 0, 0, 0, 0, 30, nullptr, nullptr, nullptr, nullptr);

  zden<<<4096, 256, 0, stream>>>(Qb, Ksum, Z);

  // G'[n,d] = sum_l Wob[n,l]*KVr[d,l], split-K x4 (K=256/slice); Wo folded in.
  dim3 gg(8, 8, 16);
  gemm_bt<EPI_NONE, false, false, false><<<gg, 256, 0, stream>>>(
      Wob, KVr, nullptr, nullptr, Pg, 1024, 1024, 256, 1024, 1024, 1024,
      0L, 1048576L, 1048576L, 0, 3, 2, nullptr, nullptr, nullptr, nullptr);
  reduce4<<<2048, 256, 0, stream>>>(Pg, Gp);

  // final: out[t,n] = Z[t]*(sum_d Qb[t,d]*G'[n,d]) + bo[n], fp32 out
  dim3 gf(32, 8, 4);
  gemm_bt<EPI_ZBIAS_F32, false, false, false><<<gf, 256, 0, stream>>>(
      Qb, Gp, bo, Z, out, 4096, 1024, 1024, 1024, 1024, 1024,
      4194304L, 1048576L, 4194304L, 4096L, 3, 30, nullptr, nullptr, nullptr, nullptr);
}

// Round 4
// 342.344 us; speedup vs baseline: 1.6558x; 1.1972x over previous
//
#include <hip/hip_runtime.h>

typedef unsigned short u16;
typedef unsigned int u32;
typedef unsigned long long u64;

typedef __attribute__((ext_vector_type(8))) short short8;   // 8 bf16 = 4 VGPRs
typedef __attribute__((ext_vector_type(4))) float floatx4;  // MFMA accumulator

__device__ __forceinline__ float b2f(u16 h) {
  u32 u = ((u32)h) << 16;
  return __builtin_bit_cast(float, u);
}
__device__ __forceinline__ u16 f2b(float f) {
  u32 u = __builtin_bit_cast(u32, f);
  u32 r = 0x7FFFu + ((u >> 16) & 1u);  // RNE
  return (u16)((u + r) >> 16);
}

// async global->LDS, 16B per lane. LDS dest = wave-uniform base + lane*16.
__device__ __forceinline__ void gl_lds16(const void* g, void* l) {
  __builtin_amdgcn_global_load_lds(
      (__attribute__((address_space(1))) void*)(u64)g,
      (__attribute__((address_space(3))) void*)(u32)(u64)l, 16, 0, 0);
}

enum { EPI_PHI_BIAS = 0, EPI_BIAS = 1, EPI_NONE = 2,
       EPI_ZBIAS_F32 = 3 };

// C[m,n] = sum_k A[m,k] * B[n,k], both bf16 K-contiguous. 128x128x32 tile,
// 4 waves (2x2, 64x64 each). 3-stage LDS ring with COUNTED vmcnt (T3+T4):
// stage(n+2) issued at top of step n (~2 K-steps latency cover); barrier waits
// vmcnt(4) (next stage stays in flight), vmcnt(0) only when nothing to prefetch.
// Waitcnt+s_barrier fused in one asm ("memory") so nothing reorders across.
// Ring safety: stage(n+2) overwrites buf(n-1); its readers drained at the
// lgkmcnt(0)+barrier ending step n-1, before stage(n+2) issues at top of n.
// vmcnt(4): 8 outstanding (stage n+1, n+2) -> wait until <=4 -> stage n+1 landed.
// LDS tiles: superrow XOR swizzle (R=r>>1, u=((r&1)<<2)|c, phys=R*8+(u^(R&7))).
// Split-K / batch: blockIdx.z: abz=bz&abmask (operand batch), kbase=(bz>>kshift)*K.
// TRANS_OUT epilogue: phi applied iff EPI==EPI_PHI_BIAS (EPI_BIAS = linear V).
template<int EPI, bool TRANS_OUT>
__global__ __launch_bounds__(256)
void gemm_bt(const u16* __restrict__ Ap, const u16* __restrict__ Bp0,
             const float* __restrict__ bias, const float* __restrict__ Zall,
             void* __restrict__ Cp,
             int M, int N, int K, int ldA, int ldB, int ldC,
             long sAb, long sBb, long sCb, long sZb, int abmask, int kshift)
{
  constexpr int BSTRIDE = 16384;                  // one ring buffer: A 8KB + B 8KB
  constexpr int BOFF    = 8192;
  constexpr int SMEM3   = 3 * BSTRIDE;            // 49152
  constexpr int SMEM    = (TRANS_OUT && 34816 > SMEM3) ? 34816 : SMEM3;
  __shared__ char smem[SMEM];

  const int tid  = threadIdx.x;
  const int lane = tid & 63;
  const int wave = tid >> 6;
  const int wm = wave >> 1, wn = wave & 1;   // 2x2 waves, 64x64 each
  const int fl = lane & 15;
  const int q  = lane >> 4;
  const int r4 = q * 4;
  const int bm0 = blockIdx.x * 128, bn0 = blockIdx.y * 128;
  const int bz = blockIdx.z;
  const int abz = bz & abmask;
  const int kbase = (bz >> kshift) * K;

  const u16* Ah = Ap  + (size_t)abz * sAb + kbase;
  const u16* Bh = Bp0 + (size_t)abz * sBb + kbase;

  // ---- staging addresses (global per-lane; LDS offsets wave-uniform for gl_lds) ----
  const u16* gA[2]; const u16* gB[2]; int sL[2];
  #pragma unroll
  for (int n = 0; n < 2; ++n) {
    int j = n * 256 + tid;                 // physical 16B slot in a tile
    int R = j >> 3, u = (j & 7) ^ (R & 7);
    int r = (R << 1) | (u >> 2), c = u & 3;
    gA[n] = Ah + (size_t)(bm0 + r) * ldA + c * 8;
    gB[n] = Bh + (size_t)(bn0 + r) * ldB + c * 8;
    sL[n] = (n * 256 + wave * 64) * 16;
  }

  // ---- fragment LDS byte offsets (within one ring buffer) ----
  int aoff[4], boff[4];
  #pragma unroll
  for (int i = 0; i < 4; ++i) {
    int ra = wm * 64 + i * 16 + fl;
    int Ra = ra >> 1, ua = ((((ra & 1) << 2) | q) ^ (Ra & 7));
    aoff[i] = (Ra * 8 + ua) * 16;
    int rb = wn * 64 + i * 16 + fl;
    int Rb = rb >> 1, ub = ((((rb & 1) << 2) | q) ^ (Rb & 7));
    boff[i] = (Rb * 8 + ub) * 16;
  }

  floatx4 zero = {0.f, 0.f, 0.f, 0.f};
  floatx4 acc[4][4];
  #pragma unroll
  for (int i = 0; i < 4; ++i)
    #pragma unroll
    for (int j = 0; j < 4; ++j) acc[i][j] = zero;

  auto stage = [&](int k0, char* base) {
    #pragma unroll
    for (int n = 0; n < 2; ++n) gl_lds16(gA[n] + k0, base + sL[n]);
    #pragma unroll
    for (int n = 0; n < 2; ++n) gl_lds16(gB[n] + k0, base + BOFF + sL[n]);
  };

  auto kstep = [&](const char* bufc) {
    short8 aF[4], bF[4];
    #pragma unroll
    for (int i = 0; i < 4; ++i) aF[i] = *(const short8*)(bufc + aoff[i]);
    #pragma unroll
    for (int i = 0; i < 4; ++i) bF[i] = *(const short8*)(bufc + BOFF + boff[i]);
    __builtin_amdgcn_s_setprio(1);
    #pragma unroll
    for (int mi = 0; mi < 4; ++mi)
      #pragma unroll
      for (int ni = 0; ni < 4; ++ni)
        acc[mi][ni] = __builtin_amdgcn_mfma_f32_16x16x32_bf16(
            aF[mi], bF[ni], acc[mi][ni], 0, 0, 0);
    __builtin_amdgcn_s_setprio(0);
  };

  const int NIT = K >> 5;                 // >=2 for all our shapes (8 or 32)
  stage(0, smem);
  stage(32, smem + BSTRIDE);
  asm volatile("s_waitcnt vmcnt(4)\ns_barrier" ::: "memory");
  int c0 = 0, c2 = 2 * BSTRIDE;
  for (int n = 0; n < NIT; ++n) {
    bool pf = n + 2 < NIT;
    if (pf) stage((n + 2) * 32, smem + c2);
    kstep(smem + c0);
    if (n + 1 < NIT) {
      if (pf) asm volatile("s_waitcnt vmcnt(4) lgkmcnt(0)\ns_barrier" ::: "memory");
      else    asm volatile("s_waitcnt vmcnt(0) lgkmcnt(0)\ns_barrier" ::: "memory");
    }
    c0 = c0 == 2 * BSTRIDE ? 0 : c0 + BSTRIDE;
    c2 = c2 == 2 * BSTRIDE ? 0 : c2 + BSTRIDE;
  }

  if constexpr (!TRANS_OUT) {
    #pragma unroll
    for (int mi = 0; mi < 4; ++mi) {
      #pragma unroll
      for (int ni = 0; ni < 4; ++ni) {
        int col = bn0 + wn * 64 + ni * 16 + fl;
        #pragma unroll
        for (int r = 0; r < 4; ++r) {
          int row = bm0 + wm * 64 + mi * 16 + r4 + r;
          float vv = acc[mi][ni][r];
          if constexpr (EPI == EPI_PHI_BIAS) {
            vv += bias[col];
            vv = __expf(-0.5f * vv * vv);
          }
          if constexpr (EPI == EPI_BIAS) vv += bias[col];
          if constexpr (EPI == EPI_ZBIAS_F32)
            vv = vv * Zall[(size_t)abz * sZb + row] + bias[col];
          if constexpr (EPI == EPI_ZBIAS_F32)
            ((float*)Cp)[(size_t)bz * sCb + (size_t)row * ldC + col] = vv;
          else
            ((u16*)Cp)[(size_t)bz * sCb + (size_t)row * ldC + col] = f2b(vv);
        }
      }
    }
  } else {
    // transpose tile through LDS, then coalesced 16B stores into [4][N][4096]
    __syncthreads();
    u16* sT = (u16*)smem;  // [128][136] = 34816 B
    #pragma unroll
    for (int mi = 0; mi < 4; ++mi) {
      #pragma unroll
      for (int ni = 0; ni < 4; ++ni) {
        int colL = wn * 64 + ni * 16 + fl;
        int row0 = wm * 64 + mi * 16 + r4;
        float bcol = bias[bn0 + colL];
        ushort4 h;
        #pragma unroll
        for (int r = 0; r < 4; ++r) {
          float vv = acc[mi][ni][r] + bcol;
          if constexpr (EPI == EPI_PHI_BIAS) vv = __expf(-0.5f * vv * vv);
          ((u16*)&h)[r] = f2b(vv);
        }
        *(ushort4*)(sT + colL * 136 + row0) = h;
      }
    }
    __syncthreads();
    #pragma unroll
    for (int i = 0; i < 8; ++i) {
      int c = tid + i * 256;                // 2048 x 16B chunks
      int dloc = c >> 4, t8 = (c & 15) * 8;
      int4 vv = *(const int4*)(sT + dloc * 136 + t8);
      int gd = bn0 + dloc;
      int gt = bm0 + t8;
      int batch = gt >> 12, tt = gt & 4095;
      *(int4*)((u16*)Cp + ((size_t)batch * N + gd) * 4096 + tt) = vv;
    }
  }
}

// fp32 -> bf16 (RNE), 16M elems, 8 per thread, 16B stores. grid 8192x256.
__global__ __launch_bounds__(256)
void fcvt(const float* __restrict__ src, u16* __restrict__ dst) {
  size_t i = ((size_t)blockIdx.x * 256 + threadIdx.x) * 8;
  float4 a = *(const float4*)(src + i);
  float4 b = *(const float4*)(src + i + 4);
  union { ushort4 h[2]; int4 v; } o;
  o.h[0].x = f2b(a.x); o.h[0].y = f2b(a.y); o.h[0].z = f2b(a.z); o.h[0].w = f2b(a.w);
  o.h[1].x = f2b(b.x); o.h[1].y = f2b(b.y); o.h[1].z = f2b(b.z); o.h[1].w = f2b(b.w);
  *(int4*)(dst + i) = o.v;
}

__global__ __launch_bounds__(256)
void wconv(const float* __restrict__ w0, const float* __restrict__ w1,
           const float* __restrict__ w2, const float* __restrict__ w3,
           u16* __restrict__ dst) {
  unsigned e = blockIdx.x * 256 + threadIdx.x;
  int mat = e >> 18;
  size_t off = (size_t)(e & 262143) * 4;
  const float* src = mat == 0 ? w0 : mat == 1 ? w1 : mat == 2 ? w2 : w3;
  float4 v = *(const float4*)(src + off);
  ushort4 h;
  h.x = f2b(v.x); h.y = f2b(v.y); h.z = f2b(v.z); h.w = f2b(v.w);
  *(ushort4*)(dst + (size_t)mat * 1048576 + off) = h;
}

// out[i] = round(sum over 4 K-slices of bf16 partials), 4M elems, slice stride 4M
__global__ __launch_bounds__(256)
void reduce4(const u16* __restrict__ P, u16* __restrict__ out) {
  size_t i = ((size_t)blockIdx.x * 256 + threadIdx.x) * 8;
  int4 a = *(const int4*)(P + i);
  int4 b = *(const int4*)(P + i + 4194304);
  int4 c = *(const int4*)(P + i + 8388608);
  int4 d = *(const int4*)(P + i + 12582912);
  const u16* ha = (const u16*)&a; const u16* hb = (const u16*)&b;
  const u16* hc = (const u16*)&c; const u16* hd = (const u16*)&d;
  ushort4 o0, o1;
  #pragma unroll
  for (int j = 0; j < 8; ++j) {
    float s = b2f(ha[j]) + b2f(hb[j]) + b2f(hc[j]) + b2f(hd[j]);
    ((u16*)(j < 4 ? &o0 : &o1))[j & 3] = f2b(s);
  }
  *(ushort4*)(out + i) = o0;
  *(ushort4*)(out + i + 4) = o1;
}

// Ksum[b*1024+d] = sum_t KT[b][d][t]; one wave per (b,d) row
__global__ __launch_bounds__(256)
void ksum_rows(const u16* __restrict__ KT, float* __restrict__ Ksum) {
  int lane = threadIdx.x & 63;
  int row = blockIdx.x * 4 + (threadIdx.x >> 6);
  const u16* p = KT + (size_t)row * 4096;
  float s = 0.f;
  #pragma unroll
  for (int i = 0; i < 8; ++i) {
    int4 d = *(const int4*)(p + i * 512 + lane * 8);
    const u16* h = (const u16*)&d;
    #pragma unroll
    for (int j = 0; j < 8; ++j) s += b2f(h[j]);
  }
  #pragma unroll
  for (int off = 32; off; off >>= 1) s += __shfl_xor(s, off, 64);
  if (lane == 0) Ksum[row] = s;
}

// Z[t] = 1/(Q[t,:]·Ksum[batch,:] + 1e-6); one wave per token
__global__ __launch_bounds__(256)
void zden(const u16* __restrict__ Qb, const float* __restrict__ Ksum,
          float* __restrict__ Z) {
  int lane = threadIdx.x & 63;
  int t = blockIdx.x * 4 + (threadIdx.x >> 6);
  const u16* qp = Qb + (size_t)t * 1024;
  const float* ks = Ksum + (size_t)(t >> 12) * 1024;
  float s = 0.f;
  #pragma unroll
  for (int i = 0; i < 2; ++i) {
    int idx = i * 512 + lane * 8;
    int4 d = *(const int4*)(qp + idx);
    const u16* h = (const u16*)&d;
    float4 k0 = *(const float4*)(ks + idx);
    float4 k1 = *(const float4*)(ks + idx + 4);
    s += b2f(h[0]) * k0.x + b2f(h[1]) * k0.y + b2f(h[2]) * k0.z + b2f(h[3]) * k0.w
       + b2f(h[4]) * k1.x + b2f(h[5]) * k1.y + b2f(h[6]) * k1.z + b2f(h[7]) * k1.w;
  }
  #pragma unroll
  for (int off = 32; off; off >>= 1) s += __shfl_xor(s, off, 64);
  if (lane == 0) Z[t] = 1.0f / (s + 1e-6f);
}

extern "C" void kernel_launch(void* const* d_in, const int* in_sizes, int n_in,
                              void* d_out, int out_size, void* d_ws, size_t ws_size,
                              hipStream_t stream) {
  const float* q  = (const float*)d_in[0];
  const float* k  = (const float*)d_in[1];
  const float* v  = (const float*)d_in[2];
  const float* Wq = (const float*)d_in[3];
  const float* bq = (const float*)d_in[4];
  const float* Wk = (const float*)d_in[5];
  const float* bk = (const float*)d_in[6];
  const float* Wv = (const float*)d_in[7];
  const float* bv = (const float*)d_in[8];
  const float* Wo = (const float*)d_in[9];
  const float* bo = (const float*)d_in[10];
  float* out = (float*)d_out;

  // workspace layout (~112.1 MiB), aliasing chain (stream-ordered, see steps):
  u16* Wqb = (u16*)d_ws;                 // 4x 1024x1024 bf16 = 8 MiB
  u16* Wkb = Wqb + 1048576;
  u16* Wvb = Wkb + 1048576;
  u16* Wob = Wvb + 1048576;
  u16* Qb  = Wob + 1048576;              // [16384][1024] bf16, 32 MiB
  u16* KT  = Qb  + 16777216;             // [4][1024][4096] bf16, 32 MiB
  u16* VT  = KT  + 16777216;             // [4][1024][4096] bf16, 32 MiB
  u16* KVr = VT  + 16777216;             // [4][1024(d)][1024(l)] bf16, 8 MiB
  float* Ksum = (float*)(KVr + 4194304); // [4][1024] f32
  float* Z    = Ksum + 4096;             // [16384] f32
  // region reuse (each write strictly after the prior reader finishes):
  u16* kb16 = Qb;   // bf16 k input; dead after Kproj
  u16* vb16 = Qb;   // bf16 v input (overwrites kb16); dead after Vproj
  u16* Pkv  = Qb;   // S2 split-K partials (overwrites vb16); dead after reduce4
  u16* Pg   = VT;   // G split-K partials (VT dead after S2)
  u16* Gp   = KT;   // G' [4][1024(n)][1024(d)] (KT dead after S2)
  u16* qb16 = VT;   // bf16 q input (Pg dead after its reduce4); dead after Qproj

  // 1. weights + k input -> bf16
  wconv<<<4096, 256, 0, stream>>>(Wq, Wk, Wv, Wo, Wqb);
  fcvt<<<8192, 256, 0, stream>>>(k, kb16);

  // 2. K projection: KT[b][d][t] = phi(k Wk^T + bk), transposed out
  dim3 gp(128, 8, 1);
  gemm_bt<EPI_PHI_BIAS, true><<<gp, 256, 0, stream>>>(
      kb16, Wkb, bk, nullptr, KT, 16384, 1024, 1024, 1024, 1024, 0,
      0, 0, 0, 0, 0, 30);
  ksum_rows<<<1024, 256, 0, stream>>>(KT, Ksum);

  // 3. V projection (vb16 overwrites kb16 region; Kproj done)
  fcvt<<<8192, 256, 0, stream>>>(v, vb16);
  gemm_bt<EPI_BIAS, true><<<gp, 256, 0, stream>>>(
      vb16, Wvb, bv, nullptr, VT, 16384, 1024, 1024, 1024, 1024, 0,
      0, 0, 0, 0, 0, 30);

  // 4. S2: KVr[d,l] = sum_t KT[d,t]*VT[l,t], split-K x4 (z = kslice*4+batch)
  dim3 g2(8, 8, 16);
  gemm_bt<EPI_NONE, false><<<g2, 256, 0, stream>>>(
      KT, VT, nullptr, nullptr, Pkv, 1024, 1024, 1024, 4096, 4096, 1024,
      4194304L, 4194304L, 1048576L, 0, 3, 2);
  reduce4<<<2048, 256, 0, stream>>>(Pkv, KVr);

  // 5. G'[n,d] = sum_l Wob[n,l]*KVr[d,l], split-K x4 (K=256/slice).
  //    Runs BEFORE Q projection so qb16 can take the VT region afterwards.
  dim3 gg(8, 8, 16);
  gemm_bt<EPI_NONE, false><<<gg, 256, 0, stream>>>(
      Wob, KVr, nullptr, nullptr, Pg, 1024, 1024, 256, 1024, 1024, 1024,
      0L, 1048576L, 1048576L, 0, 3, 2);
  reduce4<<<2048, 256, 0, stream>>>(Pg, Gp);

  // 6. Q projection (qb16 overwrites Pg region; its reduce4 done)
  fcvt<<<8192, 256, 0, stream>>>(q, qb16);
  gemm_bt<EPI_PHI_BIAS, false><<<gp, 256, 0, stream>>>(
      qb16, Wqb, bq, nullptr, Qb, 16384, 1024, 1024, 1024, 1024, 1024,
      0, 0, 0, 0, 0, 30);
  zden<<<4096, 256, 0, stream>>>(Qb, Ksum, Z);

  // 7. final: out[t,n] = Z[t]*(sum_d Qb[t,d]*G'[n,d]) + bo[n], fp32 out
  dim3 gf(32, 8, 4);
  gemm_bt<EPI_ZBIAS_F32, false><<<gf, 256, 0, stream>>>(
      Qb, Gp, bo, Z, out, 4096, 1024, 1024, 1024, 1024, 1024,
      4194304L, 1048576L, 4194304L, 4096L, 3, 30);
}

// Round 5
// 340.309 us; speedup vs baseline: 1.6657x; 1.0060x over previous
//
#include <hip/hip_runtime.h>

typedef unsigned short u16;
typedef unsigned int u32;
typedef unsigned long long u64;

typedef __attribute__((ext_vector_type(8))) short short8;   // 8 bf16 = 4 VGPRs
typedef __attribute__((ext_vector_type(4))) float floatx4;  // MFMA accumulator

__device__ __forceinline__ float b2f(u16 h) {
  u32 u = ((u32)h) << 16;
  return __builtin_bit_cast(float, u);
}
__device__ __forceinline__ u16 f2b(float f) {
  u32 u = __builtin_bit_cast(u32, f);
  u32 r = 0x7FFFu + ((u >> 16) & 1u);  // RNE
  return (u16)((u + r) >> 16);
}

// async global->LDS, 16B per lane. LDS dest = wave-uniform base + lane*16.
__device__ __forceinline__ void gl_lds16(const void* g, void* l) {
  __builtin_amdgcn_global_load_lds(
      (__attribute__((address_space(1))) void*)(u64)g,
      (__attribute__((address_space(3))) void*)(u32)(u64)l, 16, 0, 0);
}

enum { EPI_PHI_BIAS = 0, EPI_BIAS = 1, EPI_NONE = 2,
       EPI_ZBIAS_F32 = 3 };

// C[m,n] = sum_k A[m,k] * B[n,k], both bf16 K-contiguous. 128x128x32 tile,
// 4 waves (2x2, 64x64 each). 3-stage LDS ring with COUNTED vmcnt (T3+T4):
// stage(n+2) issued at top of step n (~2 K-steps latency cover); barrier waits
// vmcnt(4) (next stage stays in flight), vmcnt(0) only when nothing to prefetch.
// Waitcnt+s_barrier fused in one asm ("memory") so nothing reorders across.
// Ring safety: stage(n+2) overwrites buf(n-1); its readers drained at the
// lgkmcnt(0)+barrier ending step n-1, before stage(n+2) issues at top of n.
// vmcnt(4): 8 outstanding (stage n+1, n+2) -> wait until <=4 -> stage n+1 landed.
// LDS tiles: superrow XOR swizzle (R=r>>1, u=((r&1)<<2)|c, phys=R*8+(u^(R&7))).
// SWZ (T1, XCD-aware): wg d%8 -> XCD round-robin, so give XCD x a contiguous
// set of nbm/8 M-panels, iterating all 8 bn tiles of a panel in consecutive
// per-XCD slots: per-XCD working set = sliding A panels + full B ~ L2-sized ->
// A fetched from HBM ~once (was ~5x), staging hits L2. Requires gridDim.x%8==0
// and gridDim.y==8; bijective remap, correctness-neutral.
// Split-K / batch: blockIdx.z: abz=bz&abmask (operand batch), kbase=(bz>>kshift)*K.
// TRANS_OUT epilogue: phi applied iff EPI==EPI_PHI_BIAS (EPI_BIAS = linear V).
template<int EPI, bool TRANS_OUT, bool SWZ>
__global__ __launch_bounds__(256)
void gemm_bt(const u16* __restrict__ Ap, const u16* __restrict__ Bp0,
             const float* __restrict__ bias, const float* __restrict__ Zall,
             void* __restrict__ Cp,
             int M, int N, int K, int ldA, int ldB, int ldC,
             long sAb, long sBb, long sCb, long sZb, int abmask, int kshift)
{
  constexpr int BSTRIDE = 16384;                  // one ring buffer: A 8KB + B 8KB
  constexpr int BOFF    = 8192;
  constexpr int SMEM3   = 3 * BSTRIDE;            // 49152
  constexpr int SMEM    = (TRANS_OUT && 34816 > SMEM3) ? 34816 : SMEM3;
  __shared__ char smem[SMEM];

  const int tid  = threadIdx.x;
  const int lane = tid & 63;
  const int wave = tid >> 6;
  const int wm = wave >> 1, wn = wave & 1;   // 2x2 waves, 64x64 each
  const int fl = lane & 15;
  const int q  = lane >> 4;
  const int r4 = q * 4;

  int bx = blockIdx.x, by = blockIdx.y;
  if constexpr (SWZ) {
    int d = by * gridDim.x + bx;           // dispatch-order id within z-slice
    int xcd = d & 7, s = d >> 3;           // wg->XCD round-robins on d%8
    bx = xcd * (gridDim.x >> 3) + (s >> 3);
    by = s & 7;
  }
  const int bm0 = bx * 128, bn0 = by * 128;
  const int bz = blockIdx.z;
  const int abz = bz & abmask;
  const int kbase = (bz >> kshift) * K;

  const u16* Ah = Ap  + (size_t)abz * sAb + kbase;
  const u16* Bh = Bp0 + (size_t)abz * sBb + kbase;

  // ---- staging addresses (global per-lane; LDS offsets wave-uniform for gl_lds) ----
  const u16* gA[2]; const u16* gB[2]; int sL[2];
  #pragma unroll
  for (int n = 0; n < 2; ++n) {
    int j = n * 256 + tid;                 // physical 16B slot in a tile
    int R = j >> 3, u = (j & 7) ^ (R & 7);
    int r = (R << 1) | (u >> 2), c = u & 3;
    gA[n] = Ah + (size_t)(bm0 + r) * ldA + c * 8;
    gB[n] = Bh + (size_t)(bn0 + r) * ldB + c * 8;
    sL[n] = (n * 256 + wave * 64) * 16;
  }

  // ---- fragment LDS byte offsets (within one ring buffer) ----
  int aoff[4], boff[4];
  #pragma unroll
  for (int i = 0; i < 4; ++i) {
    int ra = wm * 64 + i * 16 + fl;
    int Ra = ra >> 1, ua = ((((ra & 1) << 2) | q) ^ (Ra & 7));
    aoff[i] = (Ra * 8 + ua) * 16;
    int rb = wn * 64 + i * 16 + fl;
    int Rb = rb >> 1, ub = ((((rb & 1) << 2) | q) ^ (Rb & 7));
    boff[i] = (Rb * 8 + ub) * 16;
  }

  floatx4 zero = {0.f, 0.f, 0.f, 0.f};
  floatx4 acc[4][4];
  #pragma unroll
  for (int i = 0; i < 4; ++i)
    #pragma unroll
    for (int j = 0; j < 4; ++j) acc[i][j] = zero;

  auto stage = [&](int k0, char* base) {
    #pragma unroll
    for (int n = 0; n < 2; ++n) gl_lds16(gA[n] + k0, base + sL[n]);
    #pragma unroll
    for (int n = 0; n < 2; ++n) gl_lds16(gB[n] + k0, base + BOFF + sL[n]);
  };

  auto kstep = [&](const char* bufc) {
    short8 aF[4], bF[4];
    #pragma unroll
    for (int i = 0; i < 4; ++i) aF[i] = *(const short8*)(bufc + aoff[i]);
    #pragma unroll
    for (int i = 0; i < 4; ++i) bF[i] = *(const short8*)(bufc + BOFF + boff[i]);
    __builtin_amdgcn_s_setprio(1);
    #pragma unroll
    for (int mi = 0; mi < 4; ++mi)
      #pragma unroll
      for (int ni = 0; ni < 4; ++ni)
        acc[mi][ni] = __builtin_amdgcn_mfma_f32_16x16x32_bf16(
            aF[mi], bF[ni], acc[mi][ni], 0, 0, 0);
    __builtin_amdgcn_s_setprio(0);
  };

  const int NIT = K >> 5;                 // >=2 for all our shapes (8 or 32)
  stage(0, smem);
  stage(32, smem + BSTRIDE);
  asm volatile("s_waitcnt vmcnt(4)\ns_barrier" ::: "memory");
  int c0 = 0, c2 = 2 * BSTRIDE;
  for (int n = 0; n < NIT; ++n) {
    bool pf = n + 2 < NIT;
    if (pf) stage((n + 2) * 32, smem + c2);
    kstep(smem + c0);
    if (n + 1 < NIT) {
      if (pf) asm volatile("s_waitcnt vmcnt(4) lgkmcnt(0)\ns_barrier" ::: "memory");
      else    asm volatile("s_waitcnt vmcnt(0) lgkmcnt(0)\ns_barrier" ::: "memory");
    }
    c0 = c0 == 2 * BSTRIDE ? 0 : c0 + BSTRIDE;
    c2 = c2 == 2 * BSTRIDE ? 0 : c2 + BSTRIDE;
  }

  if constexpr (!TRANS_OUT) {
    #pragma unroll
    for (int mi = 0; mi < 4; ++mi) {
      #pragma unroll
      for (int ni = 0; ni < 4; ++ni) {
        int col = bn0 + wn * 64 + ni * 16 + fl;
        #pragma unroll
        for (int r = 0; r < 4; ++r) {
          int row = bm0 + wm * 64 + mi * 16 + r4 + r;
          float vv = acc[mi][ni][r];
          if constexpr (EPI == EPI_PHI_BIAS) {
            vv += bias[col];
            vv = __expf(-0.5f * vv * vv);
          }
          if constexpr (EPI == EPI_BIAS) vv += bias[col];
          if constexpr (EPI == EPI_ZBIAS_F32)
            vv = vv * Zall[(size_t)abz * sZb + row] + bias[col];
          if constexpr (EPI == EPI_ZBIAS_F32)
            ((float*)Cp)[(size_t)bz * sCb + (size_t)row * ldC + col] = vv;
          else
            ((u16*)Cp)[(size_t)bz * sCb + (size_t)row * ldC + col] = f2b(vv);
        }
      }
    }
  } else {
    // transpose tile through LDS, then coalesced 16B stores into [4][N][4096]
    __syncthreads();
    u16* sT = (u16*)smem;  // [128][136] = 34816 B
    #pragma unroll
    for (int mi = 0; mi < 4; ++mi) {
      #pragma unroll
      for (int ni = 0; ni < 4; ++ni) {
        int colL = wn * 64 + ni * 16 + fl;
        int row0 = wm * 64 + mi * 16 + r4;
        float bcol = bias[bn0 + colL];
        ushort4 h;
        #pragma unroll
        for (int r = 0; r < 4; ++r) {
          float vv = acc[mi][ni][r] + bcol;
          if constexpr (EPI == EPI_PHI_BIAS) vv = __expf(-0.5f * vv * vv);
          ((u16*)&h)[r] = f2b(vv);
        }
        *(ushort4*)(sT + colL * 136 + row0) = h;
      }
    }
    __syncthreads();
    #pragma unroll
    for (int i = 0; i < 8; ++i) {
      int c = tid + i * 256;                // 2048 x 16B chunks
      int dloc = c >> 4, t8 = (c & 15) * 8;
      int4 vv = *(const int4*)(sT + dloc * 136 + t8);
      int gd = bn0 + dloc;
      int gt = bm0 + t8;
      int batch = gt >> 12, tt = gt & 4095;
      *(int4*)((u16*)Cp + ((size_t)batch * N + gd) * 4096 + tt) = vv;
    }
  }
}

// fp32 -> bf16 (RNE), 16M elems, 8 per thread, 16B stores. grid 8192x256.
__global__ __launch_bounds__(256)
void fcvt(const float* __restrict__ src, u16* __restrict__ dst) {
  size_t i = ((size_t)blockIdx.x * 256 + threadIdx.x) * 8;
  float4 a = *(const float4*)(src + i);
  float4 b = *(const float4*)(src + i + 4);
  union { ushort4 h[2]; int4 v; } o;
  o.h[0].x = f2b(a.x); o.h[0].y = f2b(a.y); o.h[0].z = f2b(a.z); o.h[0].w = f2b(a.w);
  o.h[1].x = f2b(b.x); o.h[1].y = f2b(b.y); o.h[1].z = f2b(b.z); o.h[1].w = f2b(b.w);
  *(int4*)(dst + i) = o.v;
}

__global__ __launch_bounds__(256)
void wconv(const float* __restrict__ w0, const float* __restrict__ w1,
           const float* __restrict__ w2, const float* __restrict__ w3,
           u16* __restrict__ dst) {
  unsigned e = blockIdx.x * 256 + threadIdx.x;
  int mat = e >> 18;
  size_t off = (size_t)(e & 262143) * 4;
  const float* src = mat == 0 ? w0 : mat == 1 ? w1 : mat == 2 ? w2 : w3;
  float4 v = *(const float4*)(src + off);
  ushort4 h;
  h.x = f2b(v.x); h.y = f2b(v.y); h.z = f2b(v.z); h.w = f2b(v.w);
  *(ushort4*)(dst + (size_t)mat * 1048576 + off) = h;
}

// out[i] = round(sum over 4 K-slices of bf16 partials), 4M elems, slice stride 4M
__global__ __launch_bounds__(256)
void reduce4(const u16* __restrict__ P, u16* __restrict__ out) {
  size_t i = ((size_t)blockIdx.x * 256 + threadIdx.x) * 8;
  int4 a = *(const int4*)(P + i);
  int4 b = *(const int4*)(P + i + 4194304);
  int4 c = *(const int4*)(P + i + 8388608);
  int4 d = *(const int4*)(P + i + 12582912);
  const u16* ha = (const u16*)&a; const u16* hb = (const u16*)&b;
  const u16* hc = (const u16*)&c; const u16* hd = (const u16*)&d;
  ushort4 o0, o1;
  #pragma unroll
  for (int j = 0; j < 8; ++j) {
    float s = b2f(ha[j]) + b2f(hb[j]) + b2f(hc[j]) + b2f(hd[j]);
    ((u16*)(j < 4 ? &o0 : &o1))[j & 3] = f2b(s);
  }
  *(ushort4*)(out + i) = o0;
  *(ushort4*)(out + i + 4) = o1;
}

// Ksum[b*1024+d] = sum_t KT[b][d][t]; one wave per (b,d) row
__global__ __launch_bounds__(256)
void ksum_rows(const u16* __restrict__ KT, float* __restrict__ Ksum) {
  int lane = threadIdx.x & 63;
  int row = blockIdx.x * 4 + (threadIdx.x >> 6);
  const u16* p = KT + (size_t)row * 4096;
  float s = 0.f;
  #pragma unroll
  for (int i = 0; i < 8; ++i) {
    int4 d = *(const int4*)(p + i * 512 + lane * 8);
    const u16* h = (const u16*)&d;
    #pragma unroll
    for (int j = 0; j < 8; ++j) s += b2f(h[j]);
  }
  #pragma unroll
  for (int off = 32; off; off >>= 1) s += __shfl_xor(s, off, 64);
  if (lane == 0) Ksum[row] = s;
}

// Z[t] = 1/(Q[t,:]·Ksum[batch,:] + 1e-6); one wave per token
__global__ __launch_bounds__(256)
void zden(const u16* __restrict__ Qb, const float* __restrict__ Ksum,
          float* __restrict__ Z) {
  int lane = threadIdx.x & 63;
  int t = blockIdx.x * 4 + (threadIdx.x >> 6);
  const u16* qp = Qb + (size_t)t * 1024;
  const float* ks = Ksum + (size_t)(t >> 12) * 1024;
  float s = 0.f;
  #pragma unroll
  for (int i = 0; i < 2; ++i) {
    int idx = i * 512 + lane * 8;
    int4 d = *(const int4*)(qp + idx);
    const u16* h = (const u16*)&d;
    float4 k0 = *(const float4*)(ks + idx);
    float4 k1 = *(const float4*)(ks + idx + 4);
    s += b2f(h[0]) * k0.x + b2f(h[1]) * k0.y + b2f(h[2]) * k0.z + b2f(h[3]) * k0.w
       + b2f(h[4]) * k1.x + b2f(h[5]) * k1.y + b2f(h[6]) * k1.z + b2f(h[7]) * k1.w;
  }
  #pragma unroll
  for (int off = 32; off; off >>= 1) s += __shfl_xor(s, off, 64);
  if (lane == 0) Z[t] = 1.0f / (s + 1e-6f);
}

extern "C" void kernel_launch(void* const* d_in, const int* in_sizes, int n_in,
                              void* d_out, int out_size, void* d_ws, size_t ws_size,
                              hipStream_t stream) {
  const float* q  = (const float*)d_in[0];
  const float* k  = (const float*)d_in[1];
  const float* v  = (const float*)d_in[2];
  const float* Wq = (const float*)d_in[3];
  const float* bq = (const float*)d_in[4];
  const float* Wk = (const float*)d_in[5];
  const float* bk = (const float*)d_in[6];
  const float* Wv = (const float*)d_in[7];
  const float* bv = (const float*)d_in[8];
  const float* Wo = (const float*)d_in[9];
  const float* bo = (const float*)d_in[10];
  float* out = (float*)d_out;

  // workspace layout (~112.1 MiB), aliasing chain (stream-ordered, see steps):
  u16* Wqb = (u16*)d_ws;                 // 4x 1024x1024 bf16 = 8 MiB
  u16* Wkb = Wqb + 1048576;
  u16* Wvb = Wkb + 1048576;
  u16* Wob = Wvb + 1048576;
  u16* Qb  = Wob + 1048576;              // [16384][1024] bf16, 32 MiB
  u16* KT  = Qb  + 16777216;             // [4][1024][4096] bf16, 32 MiB
  u16* VT  = KT  + 16777216;             // [4][1024][4096] bf16, 32 MiB
  u16* KVr = VT  + 16777216;             // [4][1024(d)][1024(l)] bf16, 8 MiB
  float* Ksum = (float*)(KVr + 4194304); // [4][1024] f32
  float* Z    = Ksum + 4096;             // [16384] f32
  // region reuse (each write strictly after the prior reader finishes):
  u16* kb16 = Qb;   // bf16 k input; dead after Kproj
  u16* vb16 = Qb;   // bf16 v input (overwrites kb16); dead after Vproj
  u16* Pkv  = Qb;   // S2 split-K partials (overwrites vb16); dead after reduce4
  u16* Pg   = VT;   // G split-K partials (VT dead after S2)
  u16* Gp   = KT;   // G' [4][1024(n)][1024(d)] (KT dead after S2)
  u16* qb16 = VT;   // bf16 q input (Pg dead after its reduce4); dead after Qproj

  // 1. weights + k input -> bf16
  wconv<<<4096, 256, 0, stream>>>(Wq, Wk, Wv, Wo, Wqb);
  fcvt<<<8192, 256, 0, stream>>>(k, kb16);

  // 2. K projection: KT[b][d][t] = phi(k Wk^T + bk), transposed out
  dim3 gp(128, 8, 1);
  gemm_bt<EPI_PHI_BIAS, true, true><<<gp, 256, 0, stream>>>(
      kb16, Wkb, bk, nullptr, KT, 16384, 1024, 1024, 1024, 1024, 0,
      0, 0, 0, 0, 0, 30);
  ksum_rows<<<1024, 256, 0, stream>>>(KT, Ksum);

  // 3. V projection (vb16 overwrites kb16 region; Kproj done)
  fcvt<<<8192, 256, 0, stream>>>(v, vb16);
  gemm_bt<EPI_BIAS, true, true><<<gp, 256, 0, stream>>>(
      vb16, Wvb, bv, nullptr, VT, 16384, 1024, 1024, 1024, 1024, 0,
      0, 0, 0, 0, 0, 30);

  // 4. S2: KVr[d,l] = sum_t KT[d,t]*VT[l,t], split-K x4 (z = kslice*4+batch)
  dim3 g2(8, 8, 16);
  gemm_bt<EPI_NONE, false, false><<<g2, 256, 0, stream>>>(
      KT, VT, nullptr, nullptr, Pkv, 1024, 1024, 1024, 4096, 4096, 1024,
      4194304L, 4194304L, 1048576L, 0, 3, 2);
  reduce4<<<2048, 256, 0, stream>>>(Pkv, KVr);

  // 5. G'[n,d] = sum_l Wob[n,l]*KVr[d,l], split-K x4 (K=256/slice).
  //    Runs BEFORE Q projection so qb16 can take the VT region afterwards.
  dim3 gg(8, 8, 16);
  gemm_bt<EPI_NONE, false, false><<<gg, 256, 0, stream>>>(
      Wob, KVr, nullptr, nullptr, Pg, 1024, 1024, 256, 1024, 1024, 1024,
      0L, 1048576L, 1048576L, 0, 3, 2);
  reduce4<<<2048, 256, 0, stream>>>(Pg, Gp);

  // 6. Q projection (qb16 overwrites Pg region; its reduce4 done)
  fcvt<<<8192, 256, 0, stream>>>(q, qb16);
  gemm_bt<EPI_PHI_BIAS, false, true><<<gp, 256, 0, stream>>>(
      qb16, Wqb, bq, nullptr, Qb, 16384, 1024, 1024, 1024, 1024, 1024,
      0, 0, 0, 0, 0, 30);
  zden<<<4096, 256, 0, stream>>>(Qb, Ksum, Z);

  // 7. final: out[t,n] = Z[t]*(sum_d Qb[t,d]*G'[n,d]) + bo[n], fp32 out
  dim3 gf(32, 8, 4);
  gemm_bt<EPI_ZBIAS_F32, false, true><<<gf, 256, 0, stream>>>(
      Qb, Gp, bo, Z, out, 4096, 1024, 1024, 1024, 1024, 1024,
      4194304L, 1048576L, 4194304L, 4096L, 3, 30);
}

// Round 7
// 326.409 us; speedup vs baseline: 1.7366x; 1.0426x over previous
//
#include <hip/hip_runtime.h>

typedef unsigned short u16;
typedef unsigned int u32;
typedef unsigned long long u64;

typedef __attribute__((ext_vector_type(8))) short short8;   // 8 bf16 = 4 VGPRs
typedef __attribute__((ext_vector_type(4))) float floatx4;  // MFMA accumulator

__device__ __forceinline__ float b2f(u16 h) {
  u32 u = ((u32)h) << 16;
  return __builtin_bit_cast(float, u);
}
__device__ __forceinline__ u16 f2b(float f) {
  u32 u = __builtin_bit_cast(u32, f);
  u32 r = 0x7FFFu + ((u >> 16) & 1u);  // RNE
  return (u16)((u + r) >> 16);
}

// async global->LDS, 16B per lane. LDS dest = wave-uniform base + lane*16.
__device__ __forceinline__ void gl_lds16(const void* g, void* l) {
  __builtin_amdgcn_global_load_lds(
      (__attribute__((address_space(1))) void*)(u64)g,
      (__attribute__((address_space(3))) void*)(u32)(u64)l, 16, 0, 0);
}

enum { EPI_PHI_BIAS = 0, EPI_BIAS = 1, EPI_NONE = 2,
       EPI_ZBIAS_F32 = 3 };

// ============================ 128x128 kernel (S2 / G) ========================
// C[m,n] = sum_k A[m,k]*B[n,k], bf16 K-contiguous. 128x128x32, 4 waves (2x2).
// 3-stage LDS ring, counted vmcnt(4) (see 256 kernel for invariants).
template<int EPI>
__global__ __launch_bounds__(256)
void gemm_bt(const u16* __restrict__ Ap, const u16* __restrict__ Bp0,
             const float* __restrict__ bias, const float* __restrict__ Zall,
             void* __restrict__ Cp,
             int M, int N, int K, int ldA, int ldB, int ldC,
             long sAb, long sBb, long sCb, long sZb, int abmask, int kshift)
{
  constexpr int BSTRIDE = 16384;                  // one ring buffer: A 8KB + B 8KB
  constexpr int BOFF    = 8192;
  __shared__ char smem[3 * BSTRIDE];

  const int tid  = threadIdx.x;
  const int lane = tid & 63;
  const int wave = tid >> 6;
  const int wm = wave >> 1, wn = wave & 1;   // 2x2 waves, 64x64 each
  const int fl = lane & 15;
  const int q  = lane >> 4;
  const int r4 = q * 4;
  const int bm0 = blockIdx.x * 128, bn0 = blockIdx.y * 128;
  const int bz = blockIdx.z;
  const int abz = bz & abmask;
  const int kbase = (bz >> kshift) * K;

  const u16* Ah = Ap  + (size_t)abz * sAb + kbase;
  const u16* Bh = Bp0 + (size_t)abz * sBb + kbase;

  const u16* gA[2]; const u16* gB[2]; int sL[2];
  #pragma unroll
  for (int n = 0; n < 2; ++n) {
    int j = n * 256 + tid;                 // physical 16B slot in a tile
    int R = j >> 3, u = (j & 7) ^ (R & 7);
    int r = (R << 1) | (u >> 2), c = u & 3;
    gA[n] = Ah + (size_t)(bm0 + r) * ldA + c * 8;
    gB[n] = Bh + (size_t)(bn0 + r) * ldB + c * 8;
    sL[n] = (n * 256 + wave * 64) * 16;
  }

  int aoff[4], boff[4];
  #pragma unroll
  for (int i = 0; i < 4; ++i) {
    int ra = wm * 64 + i * 16 + fl;
    int Ra = ra >> 1, ua = ((((ra & 1) << 2) | q) ^ (Ra & 7));
    aoff[i] = (Ra * 8 + ua) * 16;
    int rb = wn * 64 + i * 16 + fl;
    int Rb = rb >> 1, ub = ((((rb & 1) << 2) | q) ^ (Rb & 7));
    boff[i] = (Rb * 8 + ub) * 16;
  }

  floatx4 zero = {0.f, 0.f, 0.f, 0.f};
  floatx4 acc[4][4];
  #pragma unroll
  for (int i = 0; i < 4; ++i)
    #pragma unroll
    for (int j = 0; j < 4; ++j) acc[i][j] = zero;

  auto stage = [&](int k0, char* base) {
    #pragma unroll
    for (int n = 0; n < 2; ++n) gl_lds16(gA[n] + k0, base + sL[n]);
    #pragma unroll
    for (int n = 0; n < 2; ++n) gl_lds16(gB[n] + k0, base + BOFF + sL[n]);
  };

  auto kstep = [&](const char* bufc) {
    short8 aF[4], bF[4];
    #pragma unroll
    for (int i = 0; i < 4; ++i) aF[i] = *(const short8*)(bufc + aoff[i]);
    #pragma unroll
    for (int i = 0; i < 4; ++i) bF[i] = *(const short8*)(bufc + BOFF + boff[i]);
    __builtin_amdgcn_s_setprio(1);
    #pragma unroll
    for (int mi = 0; mi < 4; ++mi)
      #pragma unroll
      for (int ni = 0; ni < 4; ++ni)
        acc[mi][ni] = __builtin_amdgcn_mfma_f32_16x16x32_bf16(
            aF[mi], bF[ni], acc[mi][ni], 0, 0, 0);
    __builtin_amdgcn_s_setprio(0);
  };

  const int NIT = K >> 5;
  stage(0, smem);
  stage(32, smem + BSTRIDE);
  asm volatile("s_waitcnt vmcnt(4)\ns_barrier" ::: "memory");
  int c0 = 0, c2 = 2 * BSTRIDE;
  for (int n = 0; n < NIT; ++n) {
    bool pf = n + 2 < NIT;
    if (pf) stage((n + 2) * 32, smem + c2);
    kstep(smem + c0);
    if (n + 1 < NIT) {
      if (pf) asm volatile("s_waitcnt vmcnt(4) lgkmcnt(0)\ns_barrier" ::: "memory");
      else    asm volatile("s_waitcnt vmcnt(0) lgkmcnt(0)\ns_barrier" ::: "memory");
    }
    c0 = c0 == 2 * BSTRIDE ? 0 : c0 + BSTRIDE;
    c2 = c2 == 2 * BSTRIDE ? 0 : c2 + BSTRIDE;
  }

  #pragma unroll
  for (int mi = 0; mi < 4; ++mi) {
    #pragma unroll
    for (int ni = 0; ni < 4; ++ni) {
      int col = bn0 + wn * 64 + ni * 16 + fl;
      #pragma unroll
      for (int r = 0; r < 4; ++r) {
        int row = bm0 + wm * 64 + mi * 16 + r4 + r;
        float vv = acc[mi][ni][r];
        if constexpr (EPI == EPI_ZBIAS_F32) {
          vv = vv * Zall[(size_t)abz * sZb + row] + bias[col];
          ((float*)Cp)[(size_t)bz * sCb + (size_t)row * ldC + col] = vv;
        } else {
          ((u16*)Cp)[(size_t)bz * sCb + (size_t)row * ldC + col] = f2b(vv);
        }
      }
    }
  }
}

// ======================= 256x256 kernel (heavy GEMMs) ========================
// 256x256x32 tile, 8 waves (2M x 4N, each 128x64, acc[8][4]). Same proven
// elements as the 128 kernel: superrow XOR swizzle (R=r>>1, u=((r&1)<<2)|c,
// phys=R*8+(u^(R&7)); zero bank conflicts), gl_lds16 staging (4 ops/thread/
// stage -> SAME vmcnt constants), 3-stage ring with counted vmcnt:
//   prologue: stage(0), stage(1) -> 8 outstanding; vmcnt(4) => stage0 landed.
//   loop n: issue stage(n+2) [overwrites buf(n-1), readers drained at the
//   lgkmcnt(0)+barrier ending step n-1], kstep(buf n), then vmcnt(4) =>
//   stage(n+1) landed while stage(n+2) stays in flight. vmcnt(0) only at tail.
// Ratio per wave per K-step: 12 ds_read_b128 vs 32 MFMA (2x better than 128).
// B IS batched for the final GEMM (G' = [4][1024][1024]) -> sBb (R6 bug fix).
// TRANS_OUT epilogue: two 128-col passes through sT[128][264] (fits 96KB LDS).
template<int EPI, bool TRANS_OUT>
__global__ __launch_bounds__(512, 2)
void gemm_bt256(const u16* __restrict__ Ap, const u16* __restrict__ Bp0,
                const float* __restrict__ bias, const float* __restrict__ Zall,
                void* __restrict__ Cp,
                int M, int N, int K, int ldA, int ldB, int ldC,
                long sAb, long sBb, long sCb, long sZb, int abmask)
{
  constexpr int BSTRIDE = 32768;                  // A 16KB + B 16KB per stage
  constexpr int BOFF    = 16384;
  __shared__ char smem[3 * BSTRIDE];              // 96 KB -> 1 block/CU

  const int tid  = threadIdx.x;
  const int lane = tid & 63;
  const int wave = tid >> 6;
  const int wm = wave >> 2, wn = wave & 3;   // 2x4 waves, 128x64 each
  const int fl = lane & 15;
  const int q  = lane >> 4;
  const int r4 = q * 4;
  const int bm0 = blockIdx.x * 256, bn0 = blockIdx.y * 256;
  const int bz = blockIdx.z;
  const int abz = bz & abmask;

  const u16* Ah = Ap  + (size_t)abz * sAb;
  const u16* Bh = Bp0 + (size_t)abz * sBb;

  // staging: A tile 256x32 bf16 = 1024 16B slots; B same. 512 threads x2 each.
  const u16* gA[2]; const u16* gB[2]; int sL[2];
  #pragma unroll
  for (int n = 0; n < 2; ++n) {
    int j = n * 512 + tid;                   // physical 16B slot
    int R = j >> 3, u = (j & 7) ^ (R & 7);
    int r = (R << 1) | (u >> 2), c = u & 3;
    gA[n] = Ah + (size_t)(bm0 + r) * ldA + c * 8;
    gB[n] = Bh + (size_t)(bn0 + r) * ldB + c * 8;
    sL[n] = (n * 512 + wave * 64) * 16;
  }

  int aoff[8], boff[4];
  #pragma unroll
  for (int i = 0; i < 8; ++i) {
    int ra = wm * 128 + i * 16 + fl;
    int Ra = ra >> 1, ua = ((((ra & 1) << 2) | q) ^ (Ra & 7));
    aoff[i] = (Ra * 8 + ua) * 16;
  }
  #pragma unroll
  for (int i = 0; i < 4; ++i) {
    int rb = wn * 64 + i * 16 + fl;
    int Rb = rb >> 1, ub = ((((rb & 1) << 2) | q) ^ (Rb & 7));
    boff[i] = (Rb * 8 + ub) * 16;
  }

  floatx4 zero = {0.f, 0.f, 0.f, 0.f};
  floatx4 acc[8][4];
  #pragma unroll
  for (int i = 0; i < 8; ++i)
    #pragma unroll
    for (int j = 0; j < 4; ++j) acc[i][j] = zero;

  auto stage = [&](int k0, char* base) {
    #pragma unroll
    for (int n = 0; n < 2; ++n) gl_lds16(gA[n] + k0, base + sL[n]);
    #pragma unroll
    for (int n = 0; n < 2; ++n) gl_lds16(gB[n] + k0, base + BOFF + sL[n]);
  };

  auto kstep = [&](const char* bufc) {
    short8 bF[4], aF[8];
    #pragma unroll
    for (int i = 0; i < 4; ++i) bF[i] = *(const short8*)(bufc + BOFF + boff[i]);
    #pragma unroll
    for (int i = 0; i < 8; ++i) aF[i] = *(const short8*)(bufc + aoff[i]);
    __builtin_amdgcn_s_setprio(1);
    #pragma unroll
    for (int mi = 0; mi < 8; ++mi)
      #pragma unroll
      for (int ni = 0; ni < 4; ++ni)
        acc[mi][ni] = __builtin_amdgcn_mfma_f32_16x16x32_bf16(
            aF[mi], bF[ni], acc[mi][ni], 0, 0, 0);
    __builtin_amdgcn_s_setprio(0);
  };

  const int NIT = K >> 5;                    // 32 for all callers
  stage(0, smem);
  stage(32, smem + BSTRIDE);
  asm volatile("s_waitcnt vmcnt(4)\ns_barrier" ::: "memory");
  int c0 = 0, c2 = 2 * BSTRIDE;
  for (int n = 0; n < NIT; ++n) {
    bool pf = n + 2 < NIT;
    if (pf) stage((n + 2) * 32, smem + c2);
    kstep(smem + c0);
    if (n + 1 < NIT) {
      if (pf) asm volatile("s_waitcnt vmcnt(4) lgkmcnt(0)\ns_barrier" ::: "memory");
      else    asm volatile("s_waitcnt vmcnt(0) lgkmcnt(0)\ns_barrier" ::: "memory");
    }
    c0 = c0 == 2 * BSTRIDE ? 0 : c0 + BSTRIDE;
    c2 = c2 == 2 * BSTRIDE ? 0 : c2 + BSTRIDE;
  }

  if constexpr (!TRANS_OUT) {
    #pragma unroll
    for (int mi = 0; mi < 8; ++mi) {
      #pragma unroll
      for (int ni = 0; ni < 4; ++ni) {
        int col = bn0 + wn * 64 + ni * 16 + fl;
        #pragma unroll
        for (int r = 0; r < 4; ++r) {
          int row = bm0 + wm * 128 + mi * 16 + r4 + r;
          float vv = acc[mi][ni][r];
          if constexpr (EPI == EPI_PHI_BIAS) {
            vv += bias[col];
            vv = __expf(-0.5f * vv * vv);
          }
          if constexpr (EPI == EPI_ZBIAS_F32)
            vv = vv * Zall[(size_t)abz * sZb + row] + bias[col];
          if constexpr (EPI == EPI_ZBIAS_F32)
            ((float*)Cp)[(size_t)bz * sCb + (size_t)row * ldC + col] = vv;
          else
            ((u16*)Cp)[(size_t)bz * sCb + (size_t)row * ldC + col] = f2b(vv);
        }
      }
    }
  } else {
    // two passes of 128 d-cols through sT[128][264]; coalesced 16B stores
    // into C = [4][N(d)][4096(t)] bf16 (256-row tile never crosses a batch).
    u16* sT = (u16*)smem;                    // 128*264*2 = 67584 <= 96K
    #pragma unroll
    for (int p = 0; p < 2; ++p) {
      __syncthreads();                       // p=0: also drains K-loop readers
      if ((wn >> 1) == p) {
        #pragma unroll
        for (int mi = 0; mi < 8; ++mi) {
          #pragma unroll
          for (int ni = 0; ni < 4; ++ni) {
            int colL = wn * 64 + ni * 16 + fl;       // in [p*128, p*128+128)
            int row0 = wm * 128 + mi * 16 + r4;
            float bcol = bias[bn0 + colL];
            ushort4 h;
            #pragma unroll
            for (int r = 0; r < 4; ++r) {
              float vv = acc[mi][ni][r] + bcol;
              if constexpr (EPI == EPI_PHI_BIAS) vv = __expf(-0.5f * vv * vv);
              ((u16*)&h)[r] = f2b(vv);
            }
            *(ushort4*)(sT + (colL - p * 128) * 264 + row0) = h;
          }
        }
      }
      __syncthreads();
      #pragma unroll
      for (int i = 0; i < 8; ++i) {
        int c = tid + i * 512;               // 4096 x 16B chunks
        int dloc = c >> 5, t8 = (c & 31) * 8;
        int4 vv = *(const int4*)(sT + dloc * 264 + t8);
        int gd = bn0 + p * 128 + dloc;
        int gt = bm0 + t8;
        int batch = gt >> 12, tt = gt & 4095;
        *(int4*)((u16*)Cp + ((size_t)batch * N + gd) * 4096 + tt) = vv;
      }
    }
  }
}

// fp32 -> bf16 (RNE), 16M elems, 8 per thread, 16B stores. grid 8192x256.
__global__ __launch_bounds__(256)
void fcvt(const float* __restrict__ src, u16* __restrict__ dst) {
  size_t i = ((size_t)blockIdx.x * 256 + threadIdx.x) * 8;
  float4 a = *(const float4*)(src + i);
  float4 b = *(const float4*)(src + i + 4);
  union { ushort4 h[2]; int4 v; } o;
  o.h[0].x = f2b(a.x); o.h[0].y = f2b(a.y); o.h[0].z = f2b(a.z); o.h[0].w = f2b(a.w);
  o.h[1].x = f2b(b.x); o.h[1].y = f2b(b.y); o.h[1].z = f2b(b.z); o.h[1].w = f2b(b.w);
  *(int4*)(dst + i) = o.v;
}

__global__ __launch_bounds__(256)
void wconv(const float* __restrict__ w0, const float* __restrict__ w1,
           const float* __restrict__ w2, const float* __restrict__ w3,
           u16* __restrict__ dst) {
  unsigned e = blockIdx.x * 256 + threadIdx.x;
  int mat = e >> 18;
  size_t off = (size_t)(e & 262143) * 4;
  const float* src = mat == 0 ? w0 : mat == 1 ? w1 : mat == 2 ? w2 : w3;
  float4 v = *(const float4*)(src + off);
  ushort4 h;
  h.x = f2b(v.x); h.y = f2b(v.y); h.z = f2b(v.z); h.w = f2b(v.w);
  *(ushort4*)(dst + (size_t)mat * 1048576 + off) = h;
}

// out[i] = round(sum over 4 K-slices of bf16 partials), 4M elems, slice stride 4M
__global__ __launch_bounds__(256)
void reduce4(const u16* __restrict__ P, u16* __restrict__ out) {
  size_t i = ((size_t)blockIdx.x * 256 + threadIdx.x) * 8;
  int4 a = *(const int4*)(P + i);
  int4 b = *(const int4*)(P + i + 4194304);
  int4 c = *(const int4*)(P + i + 8388608);
  int4 d = *(const int4*)(P + i + 12582912);
  const u16* ha = (const u16*)&a; const u16* hb = (const u16*)&b;
  const u16* hc = (const u16*)&c; const u16* hd = (const u16*)&d;
  ushort4 o0, o1;
  #pragma unroll
  for (int j = 0; j < 8; ++j) {
    float s = b2f(ha[j]) + b2f(hb[j]) + b2f(hc[j]) + b2f(hd[j]);
    ((u16*)(j < 4 ? &o0 : &o1))[j & 3] = f2b(s);
  }
  *(ushort4*)(out + i) = o0;
  *(ushort4*)(out + i + 4) = o1;
}

// Ksum[b*1024+d] = sum_t KT[b][d][t]; one wave per (b,d) row
__global__ __launch_bounds__(256)
void ksum_rows(const u16* __restrict__ KT, float* __restrict__ Ksum) {
  int lane = threadIdx.x & 63;
  int row = blockIdx.x * 4 + (threadIdx.x >> 6);
  const u16* p = KT + (size_t)row * 4096;
  float s = 0.f;
  #pragma unroll
  for (int i = 0; i < 8; ++i) {
    int4 d = *(const int4*)(p + i * 512 + lane * 8);
    const u16* h = (const u16*)&d;
    #pragma unroll
    for (int j = 0; j < 8; ++j) s += b2f(h[j]);
  }
  #pragma unroll
  for (int off = 32; off; off >>= 1) s += __shfl_xor(s, off, 64);
  if (lane == 0) Ksum[row] = s;
}

// Z[t] = 1/(Q[t,:]·Ksum[batch,:] + 1e-6); one wave per token
__global__ __launch_bounds__(256)
void zden(const u16* __restrict__ Qb, const float* __restrict__ Ksum,
          float* __restrict__ Z) {
  int lane = threadIdx.x & 63;
  int t = blockIdx.x * 4 + (threadIdx.x >> 6);
  const u16* qp = Qb + (size_t)t * 1024;
  const float* ks = Ksum + (size_t)(t >> 12) * 1024;
  float s = 0.f;
  #pragma unroll
  for (int i = 0; i < 2; ++i) {
    int idx = i * 512 + lane * 8;
    int4 d = *(const int4*)(qp + idx);
    const u16* h = (const u16*)&d;
    float4 k0 = *(const float4*)(ks + idx);
    float4 k1 = *(const float4*)(ks + idx + 4);
    s += b2f(h[0]) * k0.x + b2f(h[1]) * k0.y + b2f(h[2]) * k0.z + b2f(h[3]) * k0.w
       + b2f(h[4]) * k1.x + b2f(h[5]) * k1.y + b2f(h[6]) * k1.z + b2f(h[7]) * k1.w;
  }
  #pragma unroll
  for (int off = 32; off; off >>= 1) s += __shfl_xor(s, off, 64);
  if (lane == 0) Z[t] = 1.0f / (s + 1e-6f);
}

extern "C" void kernel_launch(void* const* d_in, const int* in_sizes, int n_in,
                              void* d_out, int out_size, void* d_ws, size_t ws_size,
                              hipStream_t stream) {
  const float* q  = (const float*)d_in[0];
  const float* k  = (const float*)d_in[1];
  const float* v  = (const float*)d_in[2];
  const float* Wq = (const float*)d_in[3];
  const float* bq = (const float*)d_in[4];
  const float* Wk = (const float*)d_in[5];
  const float* bk = (const float*)d_in[6];
  const float* Wv = (const float*)d_in[7];
  const float* bv = (const float*)d_in[8];
  const float* Wo = (const float*)d_in[9];
  const float* bo = (const float*)d_in[10];
  float* out = (float*)d_out;

  // workspace layout (~112.1 MiB), aliasing chain (stream-ordered, see steps):
  u16* Wqb = (u16*)d_ws;                 // 4x 1024x1024 bf16 = 8 MiB
  u16* Wkb = Wqb + 1048576;
  u16* Wvb = Wkb + 1048576;
  u16* Wob = Wvb + 1048576;
  u16* Qb  = Wob + 1048576;              // [16384][1024] bf16, 32 MiB
  u16* KT  = Qb  + 16777216;             // [4][1024][4096] bf16, 32 MiB
  u16* VT  = KT  + 16777216;             // [4][1024][4096] bf16, 32 MiB
  u16* KVr = VT  + 16777216;             // [4][1024(d)][1024(l)] bf16, 8 MiB
  float* Ksum = (float*)(KVr + 4194304); // [4][1024] f32
  float* Z    = Ksum + 4096;             // [16384] f32
  // region reuse (each write strictly after the prior reader finishes):
  u16* kb16 = Qb;   // bf16 k input; dead after Kproj
  u16* vb16 = Qb;   // bf16 v input (overwrites kb16); dead after Vproj
  u16* Pkv  = Qb;   // S2 split-K partials (overwrites vb16); dead after reduce4
  u16* Pg   = VT;   // G split-K partials (VT dead after S2)
  u16* Gp   = KT;   // G' [4][1024(n)][1024(d)] (KT dead after S2)
  u16* qb16 = VT;   // bf16 q input (Pg dead after its reduce4); dead after Qproj

  // 1. weights + k input -> bf16
  wconv<<<4096, 256, 0, stream>>>(Wq, Wk, Wv, Wo, Wqb);
  fcvt<<<8192, 256, 0, stream>>>(k, kb16);

  // 2. K projection: KT[b][d][t] = phi(k Wk^T + bk), transposed out
  dim3 gp(64, 4, 1);
  gemm_bt256<EPI_PHI_BIAS, true><<<gp, 512, 0, stream>>>(
      kb16, Wkb, bk, nullptr, KT, 16384, 1024, 1024, 1024, 1024, 0,
      0, 0, 0, 0, 0);
  ksum_rows<<<1024, 256, 0, stream>>>(KT, Ksum);

  // 3. V projection (vb16 overwrites kb16 region; Kproj done)
  fcvt<<<8192, 256, 0, stream>>>(v, vb16);
  gemm_bt256<EPI_BIAS, true><<<gp, 512, 0, stream>>>(
      vb16, Wvb, bv, nullptr, VT, 16384, 1024, 1024, 1024, 1024, 0,
      0, 0, 0, 0, 0);

  // 4. S2: KVr[d,l] = sum_t KT[d,t]*VT[l,t], split-K x4 (z = kslice*4+batch)
  dim3 g2(8, 8, 16);
  gemm_bt<EPI_NONE><<<g2, 256, 0, stream>>>(
      KT, VT, nullptr, nullptr, Pkv, 1024, 1024, 1024, 4096, 4096, 1024,
      4194304L, 4194304L, 1048576L, 0, 3, 2);
  reduce4<<<2048, 256, 0, stream>>>(Pkv, KVr);

  // 5. G'[n,d] = sum_l Wob[n,l]*KVr[d,l], split-K x4 (K=256/slice).
  //    Runs BEFORE Q projection so qb16 can take the VT region afterwards.
  dim3 gg(8, 8, 16);
  gemm_bt<EPI_NONE><<<gg, 256, 0, stream>>>(
      Wob, KVr, nullptr, nullptr, Pg, 1024, 1024, 256, 1024, 1024, 1024,
      0L, 1048576L, 1048576L, 0, 3, 2);
  reduce4<<<2048, 256, 0, stream>>>(Pg, Gp);

  // 6. Q projection (qb16 overwrites Pg region; its reduce4 done)
  fcvt<<<8192, 256, 0, stream>>>(q, qb16);
  gemm_bt256<EPI_PHI_BIAS, false><<<gp, 512, 0, stream>>>(
      qb16, Wqb, bq, nullptr, Qb, 16384, 1024, 1024, 1024, 1024, 1024,
      0, 0, 0, 0, 0);
  zden<<<4096, 256, 0, stream>>>(Qb, Ksum, Z);

  // 7. final: out[t,n] = Z[t]*(sum_d Qb[t,d]*G'[n,d]) + bo[n], fp32 out
  dim3 gf(16, 4, 4);
  gemm_bt256<EPI_ZBIAS_F32, false><<<gf, 512, 0, stream>>>(
      Qb, Gp, bo, Z, out, 4096, 1024, 1024, 1024, 1024, 1024,
      4194304L, 1048576L, 4194304L, 4096L, 3);
}

// Round 8
// 309.793 us; speedup vs baseline: 1.8298x; 1.0536x over previous
//
#include <hip/hip_runtime.h>

typedef unsigned short u16;
typedef unsigned int u32;
typedef unsigned long long u64;

typedef __attribute__((ext_vector_type(8))) short short8;   // 8 bf16 = 4 VGPRs
typedef __attribute__((ext_vector_type(4))) float floatx4;  // MFMA accumulator

__device__ __forceinline__ float b2f(u16 h) {
  u32 u = ((u32)h) << 16;
  return __builtin_bit_cast(float, u);
}
__device__ __forceinline__ u16 f2b(float f) {
  u32 u = __builtin_bit_cast(u32, f);
  u32 r = 0x7FFFu + ((u >> 16) & 1u);  // RNE
  return (u16)((u + r) >> 16);
}

// async global->LDS, 16B per lane. LDS dest = wave-uniform base + lane*16.
__device__ __forceinline__ void gl_lds16(const void* g, void* l) {
  __builtin_amdgcn_global_load_lds(
      (__attribute__((address_space(1))) void*)(u64)g,
      (__attribute__((address_space(3))) void*)(u32)(u64)l, 16, 0, 0);
}

enum { EPI_PHI_BIAS = 0, EPI_BIAS = 1, EPI_NONE = 2,
       EPI_ZBIAS_F32 = 3 };

// ==================== 256x256 kernel (ALL GEMMs) =============================
// 256x256x32 tile, 8 waves (2M x 4N, each 128x64, acc[8][4]). Proven elements:
// superrow XOR swizzle (R=r>>1, u=((r&1)<<2)|c, phys=R*8+(u^(R&7)); zero bank
// conflicts), gl_lds16 staging (4 ops/thread/stage), 3-stage ring with counted
// vmcnt:
//   prologue: stage(0), stage(1) -> 8 outstanding; vmcnt(4) => stage0 landed.
//   loop n: issue stage(n+2) [overwrites buf(n-1), readers drained at the
//   lgkmcnt(0)+barrier ending step n-1], kstep(buf n), then vmcnt(4) =>
//   stage(n+1) landed while stage(n+2) stays in flight. vmcnt(0) only at tail.
// Ratio per wave per K-step: 12 ds_read_b128 vs 32 MFMA.
// Split-K / batch (R8): abz = bz & abmask selects operand batch; kbase =
// (bz >> kshift) * K selects the K-slice (S2: kshift=2, 4 slices x 4 batches).
// B batched via sBb (final GEMM: G' = [4][1024][1024]).
// TRANS_OUT epilogue: two 128-col passes through sT[128][264] (fits 96KB LDS).
template<int EPI, bool TRANS_OUT>
__global__ __launch_bounds__(512, 2)
void gemm_bt256(const u16* __restrict__ Ap, const u16* __restrict__ Bp0,
                const float* __restrict__ bias, const float* __restrict__ Zall,
                void* __restrict__ Cp,
                int M, int N, int K, int ldA, int ldB, int ldC,
                long sAb, long sBb, long sCb, long sZb, int abmask, int kshift)
{
  constexpr int BSTRIDE = 32768;                  // A 16KB + B 16KB per stage
  constexpr int BOFF    = 16384;
  __shared__ char smem[3 * BSTRIDE];              // 96 KB -> 1 block/CU

  const int tid  = threadIdx.x;
  const int lane = tid & 63;
  const int wave = tid >> 6;
  const int wm = wave >> 2, wn = wave & 3;   // 2x4 waves, 128x64 each
  const int fl = lane & 15;
  const int q  = lane >> 4;
  const int r4 = q * 4;
  const int bm0 = blockIdx.x * 256, bn0 = blockIdx.y * 256;
  const int bz = blockIdx.z;
  const int abz = bz & abmask;
  const int kbase = (bz >> kshift) * K;

  const u16* Ah = Ap  + (size_t)abz * sAb + kbase;
  const u16* Bh = Bp0 + (size_t)abz * sBb + kbase;

  // staging: A tile 256x32 bf16 = 1024 16B slots; B same. 512 threads x2 each.
  const u16* gA[2]; const u16* gB[2]; int sL[2];
  #pragma unroll
  for (int n = 0; n < 2; ++n) {
    int j = n * 512 + tid;                   // physical 16B slot
    int R = j >> 3, u = (j & 7) ^ (R & 7);
    int r = (R << 1) | (u >> 2), c = u & 3;
    gA[n] = Ah + (size_t)(bm0 + r) * ldA + c * 8;
    gB[n] = Bh + (size_t)(bn0 + r) * ldB + c * 8;
    sL[n] = (n * 512 + wave * 64) * 16;
  }

  int aoff[8], boff[4];
  #pragma unroll
  for (int i = 0; i < 8; ++i) {
    int ra = wm * 128 + i * 16 + fl;
    int Ra = ra >> 1, ua = ((((ra & 1) << 2) | q) ^ (Ra & 7));
    aoff[i] = (Ra * 8 + ua) * 16;
  }
  #pragma unroll
  for (int i = 0; i < 4; ++i) {
    int rb = wn * 64 + i * 16 + fl;
    int Rb = rb >> 1, ub = ((((rb & 1) << 2) | q) ^ (Rb & 7));
    boff[i] = (Rb * 8 + ub) * 16;
  }

  floatx4 zero = {0.f, 0.f, 0.f, 0.f};
  floatx4 acc[8][4];
  #pragma unroll
  for (int i = 0; i < 8; ++i)
    #pragma unroll
    for (int j = 0; j < 4; ++j) acc[i][j] = zero;

  auto stage = [&](int k0, char* base) {
    #pragma unroll
    for (int n = 0; n < 2; ++n) gl_lds16(gA[n] + k0, base + sL[n]);
    #pragma unroll
    for (int n = 0; n < 2; ++n) gl_lds16(gB[n] + k0, base + BOFF + sL[n]);
  };

  auto kstep = [&](const char* bufc) {
    short8 bF[4], aF[8];
    #pragma unroll
    for (int i = 0; i < 4; ++i) bF[i] = *(const short8*)(bufc + BOFF + boff[i]);
    #pragma unroll
    for (int i = 0; i < 8; ++i) aF[i] = *(const short8*)(bufc + aoff[i]);
    __builtin_amdgcn_s_setprio(1);
    #pragma unroll
    for (int mi = 0; mi < 8; ++mi)
      #pragma unroll
      for (int ni = 0; ni < 4; ++ni)
        acc[mi][ni] = __builtin_amdgcn_mfma_f32_16x16x32_bf16(
            aF[mi], bF[ni], acc[mi][ni], 0, 0, 0);
    __builtin_amdgcn_s_setprio(0);
  };

  const int NIT = K >> 5;                    // 32 (proj/S2/final) or 8 (G)
  stage(0, smem);
  stage(32, smem + BSTRIDE);
  asm volatile("s_waitcnt vmcnt(4)\ns_barrier" ::: "memory");
  int c0 = 0, c2 = 2 * BSTRIDE;
  for (int n = 0; n < NIT; ++n) {
    bool pf = n + 2 < NIT;
    if (pf) stage((n + 2) * 32, smem + c2);
    kstep(smem + c0);
    if (n + 1 < NIT) {
      if (pf) asm volatile("s_waitcnt vmcnt(4) lgkmcnt(0)\ns_barrier" ::: "memory");
      else    asm volatile("s_waitcnt vmcnt(0) lgkmcnt(0)\ns_barrier" ::: "memory");
    }
    c0 = c0 == 2 * BSTRIDE ? 0 : c0 + BSTRIDE;
    c2 = c2 == 2 * BSTRIDE ? 0 : c2 + BSTRIDE;
  }

  if constexpr (!TRANS_OUT) {
    #pragma unroll
    for (int mi = 0; mi < 8; ++mi) {
      #pragma unroll
      for (int ni = 0; ni < 4; ++ni) {
        int col = bn0 + wn * 64 + ni * 16 + fl;
        #pragma unroll
        for (int r = 0; r < 4; ++r) {
          int row = bm0 + wm * 128 + mi * 16 + r4 + r;
          float vv = acc[mi][ni][r];
          if constexpr (EPI == EPI_PHI_BIAS) {
            vv += bias[col];
            vv = __expf(-0.5f * vv * vv);
          }
          if constexpr (EPI == EPI_ZBIAS_F32)
            vv = vv * Zall[(size_t)abz * sZb + row] + bias[col];
          if constexpr (EPI == EPI_ZBIAS_F32)
            ((float*)Cp)[(size_t)bz * sCb + (size_t)row * ldC + col] = vv;
          else
            ((u16*)Cp)[(size_t)bz * sCb + (size_t)row * ldC + col] = f2b(vv);
        }
      }
    }
  } else {
    // two passes of 128 d-cols through sT[128][264]; coalesced 16B stores
    // into C = [4][N(d)][4096(t)] bf16 (256-row tile never crosses a batch).
    u16* sT = (u16*)smem;                    // 128*264*2 = 67584 <= 96K
    #pragma unroll
    for (int p = 0; p < 2; ++p) {
      __syncthreads();                       // p=0: also drains K-loop readers
      if ((wn >> 1) == p) {
        #pragma unroll
        for (int mi = 0; mi < 8; ++mi) {
          #pragma unroll
          for (int ni = 0; ni < 4; ++ni) {
            int colL = wn * 64 + ni * 16 + fl;       // in [p*128, p*128+128)
            int row0 = wm * 128 + mi * 16 + r4;
            float bcol = bias[bn0 + colL];
            ushort4 h;
            #pragma unroll
            for (int r = 0; r < 4; ++r) {
              float vv = acc[mi][ni][r] + bcol;
              if constexpr (EPI == EPI_PHI_BIAS) vv = __expf(-0.5f * vv * vv);
              ((u16*)&h)[r] = f2b(vv);
            }
            *(ushort4*)(sT + (colL - p * 128) * 264 + row0) = h;
          }
        }
      }
      __syncthreads();
      #pragma unroll
      for (int i = 0; i < 8; ++i) {
        int c = tid + i * 512;               // 4096 x 16B chunks
        int dloc = c >> 5, t8 = (c & 31) * 8;
        int4 vv = *(const int4*)(sT + dloc * 264 + t8);
        int gd = bn0 + p * 128 + dloc;
        int gt = bm0 + t8;
        int batch = gt >> 12, tt = gt & 4095;
        *(int4*)((u16*)Cp + ((size_t)batch * N + gd) * 4096 + tt) = vv;
      }
    }
  }
}

// fp32 -> bf16 (RNE), 16M elems, 8 per thread, 16B stores. grid 8192x256.
__global__ __launch_bounds__(256)
void fcvt(const float* __restrict__ src, u16* __restrict__ dst) {
  size_t i = ((size_t)blockIdx.x * 256 + threadIdx.x) * 8;
  float4 a = *(const float4*)(src + i);
  float4 b = *(const float4*)(src + i + 4);
  union { ushort4 h[2]; int4 v; } o;
  o.h[0].x = f2b(a.x); o.h[0].y = f2b(a.y); o.h[0].z = f2b(a.z); o.h[0].w = f2b(a.w);
  o.h[1].x = f2b(b.x); o.h[1].y = f2b(b.y); o.h[1].z = f2b(b.z); o.h[1].w = f2b(b.w);
  *(int4*)(dst + i) = o.v;
}

__global__ __launch_bounds__(256)
void wconv(const float* __restrict__ w0, const float* __restrict__ w1,
           const float* __restrict__ w2, const float* __restrict__ w3,
           u16* __restrict__ dst) {
  unsigned e = blockIdx.x * 256 + threadIdx.x;
  int mat = e >> 18;
  size_t off = (size_t)(e & 262143) * 4;
  const float* src = mat == 0 ? w0 : mat == 1 ? w1 : mat == 2 ? w2 : w3;
  float4 v = *(const float4*)(src + off);
  ushort4 h;
  h.x = f2b(v.x); h.y = f2b(v.y); h.z = f2b(v.z); h.w = f2b(v.w);
  *(ushort4*)(dst + (size_t)mat * 1048576 + off) = h;
}

// out[i] = round(sum over 4 K-slices of bf16 partials), 4M elems, slice stride 4M
__global__ __launch_bounds__(256)
void reduce4(const u16* __restrict__ P, u16* __restrict__ out) {
  size_t i = ((size_t)blockIdx.x * 256 + threadIdx.x) * 8;
  int4 a = *(const int4*)(P + i);
  int4 b = *(const int4*)(P + i + 4194304);
  int4 c = *(const int4*)(P + i + 8388608);
  int4 d = *(const int4*)(P + i + 12582912);
  const u16* ha = (const u16*)&a; const u16* hb = (const u16*)&b;
  const u16* hc = (const u16*)&c; const u16* hd = (const u16*)&d;
  ushort4 o0, o1;
  #pragma unroll
  for (int j = 0; j < 8; ++j) {
    float s = b2f(ha[j]) + b2f(hb[j]) + b2f(hc[j]) + b2f(hd[j]);
    ((u16*)(j < 4 ? &o0 : &o1))[j & 3] = f2b(s);
  }
  *(ushort4*)(out + i) = o0;
  *(ushort4*)(out + i + 4) = o1;
}

// Ksum[b*1024+d] = sum_t KT[b][d][t]; one wave per (b,d) row
__global__ __launch_bounds__(256)
void ksum_rows(const u16* __restrict__ KT, float* __restrict__ Ksum) {
  int lane = threadIdx.x & 63;
  int row = blockIdx.x * 4 + (threadIdx.x >> 6);
  const u16* p = KT + (size_t)row * 4096;
  float s = 0.f;
  #pragma unroll
  for (int i = 0; i < 8; ++i) {
    int4 d = *(const int4*)(p + i * 512 + lane * 8);
    const u16* h = (const u16*)&d;
    #pragma unroll
    for (int j = 0; j < 8; ++j) s += b2f(h[j]);
  }
  #pragma unroll
  for (int off = 32; off; off >>= 1) s += __shfl_xor(s, off, 64);
  if (lane == 0) Ksum[row] = s;
}

// Z[t] = 1/(Q[t,:]·Ksum[batch,:] + 1e-6); one wave per token
__global__ __launch_bounds__(256)
void zden(const u16* __restrict__ Qb, const float* __restrict__ Ksum,
          float* __restrict__ Z) {
  int lane = threadIdx.x & 63;
  int t = blockIdx.x * 4 + (threadIdx.x >> 6);
  const u16* qp = Qb + (size_t)t * 1024;
  const float* ks = Ksum + (size_t)(t >> 12) * 1024;
  float s = 0.f;
  #pragma unroll
  for (int i = 0; i < 2; ++i) {
    int idx = i * 512 + lane * 8;
    int4 d = *(const int4*)(qp + idx);
    const u16* h = (const u16*)&d;
    float4 k0 = *(const float4*)(ks + idx);
    float4 k1 = *(const float4*)(ks + idx + 4);
    s += b2f(h[0]) * k0.x + b2f(h[1]) * k0.y + b2f(h[2]) * k0.z + b2f(h[3]) * k0.w
       + b2f(h[4]) * k1.x + b2f(h[5]) * k1.y + b2f(h[6]) * k1.z + b2f(h[7]) * k1.w;
  }
  #pragma unroll
  for (int off = 32; off; off >>= 1) s += __shfl_xor(s, off, 64);
  if (lane == 0) Z[t] = 1.0f / (s + 1e-6f);
}

extern "C" void kernel_launch(void* const* d_in, const int* in_sizes, int n_in,
                              void* d_out, int out_size, void* d_ws, size_t ws_size,
                              hipStream_t stream) {
  const float* q  = (const float*)d_in[0];
  const float* k  = (const float*)d_in[1];
  const float* v  = (const float*)d_in[2];
  const float* Wq = (const float*)d_in[3];
  const float* bq = (const float*)d_in[4];
  const float* Wk = (const float*)d_in[5];
  const float* bk = (const float*)d_in[6];
  const float* Wv = (const float*)d_in[7];
  const float* bv = (const float*)d_in[8];
  const float* Wo = (const float*)d_in[9];
  const float* bo = (const float*)d_in[10];
  float* out = (float*)d_out;

  // workspace layout (~112.1 MiB), aliasing chain (stream-ordered, see steps):
  u16* Wqb = (u16*)d_ws;                 // 4x 1024x1024 bf16 = 8 MiB
  u16* Wkb = Wqb + 1048576;
  u16* Wvb = Wkb + 1048576;
  u16* Wob = Wvb + 1048576;
  u16* Qb  = Wob + 1048576;              // [16384][1024] bf16, 32 MiB
  u16* KT  = Qb  + 16777216;             // [4][1024][4096] bf16, 32 MiB
  u16* VT  = KT  + 16777216;             // [4][1024][4096] bf16, 32 MiB
  u16* KVr = VT  + 16777216;             // [4][1024(d)][1024(l)] bf16, 8 MiB
  float* Ksum = (float*)(KVr + 4194304); // [4][1024] f32
  float* Z    = Ksum + 4096;             // [16384] f32
  // region reuse (each write strictly after the prior reader finishes):
  u16* kb16 = Qb;   // bf16 k input; dead after Kproj
  u16* vb16 = Qb;   // bf16 v input (overwrites kb16); dead after Vproj
  u16* Pkv  = Qb;   // S2 split-K partials (overwrites vb16); dead after reduce4
  u16* Pg   = VT;   // G split-K partials (VT dead after S2)
  u16* Gp   = KT;   // G' [4][1024(n)][1024(d)] (KT dead after S2)
  u16* qb16 = VT;   // bf16 q input (Pg dead after its reduce4); dead after Qproj

  // 1. weights + k input -> bf16
  wconv<<<4096, 256, 0, stream>>>(Wq, Wk, Wv, Wo, Wqb);
  fcvt<<<8192, 256, 0, stream>>>(k, kb16);

  // 2. K projection: KT[b][d][t] = phi(k Wk^T + bk), transposed out
  dim3 gp(64, 4, 1);
  gemm_bt256<EPI_PHI_BIAS, true><<<gp, 512, 0, stream>>>(
      kb16, Wkb, bk, nullptr, KT, 16384, 1024, 1024, 1024, 1024, 0,
      0, 0, 0, 0, 0, 2);
  ksum_rows<<<1024, 256, 0, stream>>>(KT, Ksum);

  // 3. V projection (vb16 overwrites kb16 region; Kproj done)
  fcvt<<<8192, 256, 0, stream>>>(v, vb16);
  gemm_bt256<EPI_BIAS, true><<<gp, 512, 0, stream>>>(
      vb16, Wvb, bv, nullptr, VT, 16384, 1024, 1024, 1024, 1024, 0,
      0, 0, 0, 0, 0, 2);

  // 4. S2: KVr[d,l] = sum_t KT[d,t]*VT[l,t], split-K x4 (z = kslice*4+batch)
  dim3 g2(4, 4, 16);
  gemm_bt256<EPI_NONE, false><<<g2, 512, 0, stream>>>(
      KT, VT, nullptr, nullptr, Pkv, 1024, 1024, 1024, 4096, 4096, 1024,
      4194304L, 4194304L, 1048576L, 0, 3, 2);
  reduce4<<<2048, 256, 0, stream>>>(Pkv, KVr);

  // 5. G'[n,d] = sum_l Wob[n,l]*KVr[d,l], split-K x4 (K=256/slice).
  //    Runs BEFORE Q projection so qb16 can take the VT region afterwards.
  dim3 gg(4, 4, 16);
  gemm_bt256<EPI_NONE, false><<<gg, 512, 0, stream>>>(
      Wob, KVr, nullptr, nullptr, Pg, 1024, 1024, 256, 1024, 1024, 1024,
      0L, 1048576L, 1048576L, 0, 3, 2);
  reduce4<<<2048, 256, 0, stream>>>(Pg, Gp);

  // 6. Q projection (qb16 overwrites Pg region; its reduce4 done)
  fcvt<<<8192, 256, 0, stream>>>(q, qb16);
  gemm_bt256<EPI_PHI_BIAS, false><<<gp, 512, 0, stream>>>(
      qb16, Wqb, bq, nullptr, Qb, 16384, 1024, 1024, 1024, 1024, 1024,
      0, 0, 0, 0, 0, 2);
  zden<<<4096, 256, 0, stream>>>(Qb, Ksum, Z);

  // 7. final: out[t,n] = Z[t]*(sum_d Qb[t,d]*G'[n,d]) + bo[n], fp32 out
  dim3 gf(16, 4, 4);
  gemm_bt256<EPI_ZBIAS_F32, false><<<gf, 512, 0, stream>>>(
      Qb, Gp, bo, Z, out, 4096, 1024, 1024, 1024, 1024, 1024,
      4194304L, 1048576L, 4194304L, 4096L, 3, 2);
}